// Round 7
// baseline (295.329 us; speedup 1.0000x reference)
//
#include <hip/hip_runtime.h>
#include <cstdint>
#include <cstddef>

typedef __attribute__((ext_vector_type(8))) short short8;
typedef __attribute__((ext_vector_type(4))) short short4v;
typedef __attribute__((ext_vector_type(4))) float f32x4;
typedef unsigned short u16;

#define DI __device__ __forceinline__

// ---------------- problem constants ----------------
constexpr int BATCH = 4;
constexpr int HEADS = 12, HD = 64;
constexpr int NTOK = 1569;          // T*H*W + 1
constexpr int NPAD = 1600;          // kv pad (25*64), qkvf row pad
constexpr int QPAD = 1664;          // q pad (13*128)
constexpr int DIM = 768, DIM3 = 2304;
constexpr int MROWS = BATCH * NTOK; // 6276
constexpr int MP = 6400;            // 50 * 128
constexpr int AUG = 128;            // 64 ch + 8 + 14 + 14 + pad
constexpr int BHN = BATCH * HEADS;  // 48
constexpr float LOG2E = 1.4426950408889634f;
constexpr float QSCALE = 0.125f * LOG2E;  // attn scale folded with log2e (exp2 domain)
constexpr float RESID = 8.0f / LOG2E;     // 1/QSCALE
constexpr float LN_EPS = 1e-5f;
constexpr int SLAB = NPAD * HD;           // 102400 elems per (tau,bh) slab

// ---------------- helpers ----------------
DI u16 f2bf(float x) {
  union { float f; unsigned u; } v; v.f = x;
  unsigned r = v.u + 0x7FFFu + ((v.u >> 16) & 1u);
  return (u16)(r >> 16);
}
DI float bf2f(u16 h) {
  union { unsigned u; float f; } v; v.u = ((unsigned)h) << 16;
  return v.f;
}

typedef const __attribute__((address_space(1))) unsigned int gu32;
typedef __attribute__((address_space(3))) unsigned int lu32;
DI void gld16(const void* g, void* l) {
  __builtin_amdgcn_global_load_lds((gu32*)g, (lu32*)l, 16, 0, 0);
}

// full 64-lane sum: 4 DPP row_ror levels (VALU pipe) + xor16/xor32 cross-row
DI float redsum64(float x) {
  int t;
  t = __builtin_amdgcn_update_dpp(__float_as_int(x), __float_as_int(x), 0x121, 0xF, 0xF, false);
  x += __int_as_float(t);
  t = __builtin_amdgcn_update_dpp(__float_as_int(x), __float_as_int(x), 0x122, 0xF, 0xF, false);
  x += __int_as_float(t);
  t = __builtin_amdgcn_update_dpp(__float_as_int(x), __float_as_int(x), 0x124, 0xF, 0xF, false);
  x += __int_as_float(t);
  t = __builtin_amdgcn_update_dpp(__float_as_int(x), __float_as_int(x), 0x128, 0xF, 0xF, false);
  x += __int_as_float(t);
  x += __shfl_xor(x, 16);
  x += __shfl_xor(x, 32);
  return x;
}

// ---------------- cast kernels ----------------
__global__ __launch_bounds__(256) void k_cast_x(const float* __restrict__ x,
                                                u16* __restrict__ xb) {
  int i = (blockIdx.x * 256 + threadIdx.x) * 4;
  if (i >= MP * DIM) return;
  int row = i / DIM;
  short4v o;
  if (row < MROWS) {
    float4 v = *(const float4*)(x + i);
    o.x = (short)f2bf(v.x); o.y = (short)f2bf(v.y);
    o.z = (short)f2bf(v.z); o.w = (short)f2bf(v.w);
  } else {
    o.x = 0; o.y = 0; o.z = 0; o.w = 0;
  }
  *(short4v*)(xb + i) = o;
}

// dst (NC, K) bf16 = transpose of src (K, NC) f32 — LDS 32x32 tile transpose
__global__ __launch_bounds__(256) void k_transpose_cast(const float* __restrict__ src,
                                                        u16* __restrict__ dst,
                                                        int K, int NC) {
  __shared__ float tile[32][33];
  const int ntiles = NC >> 5;
  const int bx = blockIdx.x % ntiles;  // n-tile
  const int by = blockIdx.x / ntiles;  // k-tile
  const int tx = threadIdx.x & 31, ty = threadIdx.x >> 5;
  const int n0 = bx * 32, k0 = by * 32;
#pragma unroll
  for (int r = 0; r < 32; r += 8)
    tile[ty + r][tx] = src[(size_t)(k0 + ty + r) * NC + n0 + tx];
  __syncthreads();
#pragma unroll
  for (int r = 0; r < 32; r += 8)
    dst[(size_t)(n0 + ty + r) * K + k0 + tx] = f2bf(tile[tx][ty + r]);
}

// ---------------- GEMM: C(M,N) = A(M,768)*Bt(N,768)^T + bias ----------------
// EPI 0: scatter bf16 to qkv ws (t,b,h,n,c).  EPI 1: linear f32 out (proj).
template <int EPI>
__global__ __launch_bounds__(256) void k_gemm(const u16* __restrict__ A,
                                              const u16* __restrict__ Bt,
                                              const float* __restrict__ bias,
                                              void* __restrict__ outv) {
  __shared__ __align__(16) u16 sA[128 * 64];
  __shared__ __align__(16) u16 sB[128 * 64];
  const int tid = threadIdx.x;
  const int w = tid >> 6, lane = tid & 63;
  const int g = lane >> 4, lr = lane & 15;
  const int brow = blockIdx.x * 128, bcol = blockIdx.y * 128;
  const int wr = w >> 1, wc = w & 1;

  f32x4 acc[4][4];
#pragma unroll
  for (int m = 0; m < 4; ++m)
#pragma unroll
    for (int n = 0; n < 4; ++n) {
      acc[m][n].x = 0.f; acc[m][n].y = 0.f; acc[m][n].z = 0.f; acc[m][n].w = 0.f;
    }

  for (int kt = 0; kt < 12; ++kt) {
    __syncthreads();
#pragma unroll
    for (int j = 0; j < 4; ++j) {
      int cb = (j * 4 + w) * 64;
      int chunk = cb + lane;
      int row = chunk >> 3, ch = chunk & 7;
      int gch = ch ^ (row & 7);
      gld16(A + (size_t)(brow + row) * DIM + kt * 64 + gch * 8, &sA[cb * 8]);
      gld16(Bt + (size_t)(bcol + row) * DIM + kt * 64 + gch * 8, &sB[cb * 8]);
    }
    __syncthreads();

    short8 af[4][2], bfr[4][2];
#pragma unroll
    for (int m = 0; m < 4; ++m) {
      int row = wr * 64 + m * 16 + lr;
      int sw = row & 7;
#pragma unroll
      for (int ks = 0; ks < 2; ++ks)
        af[m][ks] = *(const short8*)&sA[row * 64 + (((ks * 4 + g) ^ sw) * 8)];
    }
#pragma unroll
    for (int n = 0; n < 4; ++n) {
      int row = wc * 64 + n * 16 + lr;
      int sw = row & 7;
#pragma unroll
      for (int ks = 0; ks < 2; ++ks)
        bfr[n][ks] = *(const short8*)&sB[row * 64 + (((ks * 4 + g) ^ sw) * 8)];
    }
#pragma unroll
    for (int m = 0; m < 4; ++m)
#pragma unroll
      for (int n = 0; n < 4; ++n) {
        acc[m][n] = __builtin_amdgcn_mfma_f32_16x16x32_bf16(af[m][0], bfr[n][0], acc[m][n], 0, 0, 0);
        acc[m][n] = __builtin_amdgcn_mfma_f32_16x16x32_bf16(af[m][1], bfr[n][1], acc[m][n], 0, 0, 0);
      }
  }

#pragma unroll
  for (int m = 0; m < 4; ++m)
#pragma unroll
    for (int n = 0; n < 4; ++n) {
      int gj = bcol + wc * 64 + n * 16 + lr;
      float bv = bias[gj];
#pragma unroll
      for (int r = 0; r < 4; ++r) {
        int gm = brow + wr * 64 + m * 16 + g * 4 + r;
        if (gm >= MROWS) continue;
        float v = acc[m][n][r] + bv;
        if (EPI == 0) {
          int t = gj >= 1536 ? 2 : (gj >= 768 ? 1 : 0);
          int rem = gj - t * 768;
          int h = rem >> 6, c = rem & 63;
          int b = gm >= 3 * NTOK ? 3 : (gm >= 2 * NTOK ? 2 : (gm >= NTOK ? 1 : 0));
          int nt = gm - b * NTOK;
          ((u16*)outv)[(((size_t)(t * BATCH + b) * HEADS + h) * NPAD + nt) * HD + c] = f2bf(v);
        } else {
          ((float*)outv)[(size_t)gm * DIM + gj] = v;
        }
      }
    }
}

// ---------------- pool (depthwise conv3d) + LN + aug writes ----------------
// Wave = one (tau, bh, t, h) row; slides 3x3x3 window along w. bf16 input,
// zero-page redirect for out-of-range rows (no per-tap bounds checks).
__global__ __launch_bounds__(256, 6) void k_pool(
    const u16* __restrict__ qkv,   // bf16 slabs + zero page at end
    const float* __restrict__ pw_q, const float* __restrict__ pw_k, const float* __restrict__ pw_v,
    const float* __restrict__ nw_q, const float* __restrict__ nb_q,
    const float* __restrict__ nw_k, const float* __restrict__ nb_k,
    const float* __restrict__ nw_v, const float* __restrict__ nb_v,
    u16* __restrict__ Qa, u16* __restrict__ Ka, u16* __restrict__ Vt) {
  const int wv = threadIdx.x >> 6, lane = threadIdx.x & 63;
  const int unit = blockIdx.x % 29;
  const int taubh = blockIdx.x / 29;
  const int tau = taubh / BHN, bh = taubh % BHN;
  const u16* src = qkv + (size_t)taubh * SLAB;
  const int zoff = (3 * BHN - taubh) * SLAB;   // zero page offset from src (elems)
  const float* nw = tau == 0 ? nw_q : tau == 1 ? nw_k : nw_v;
  const float* nb = tau == 0 ? nb_q : tau == 1 ? nb_k : nb_v;

  if (unit == 28) {
    if (wv == 0) {
      // CLS token (n = 0)
      float val = bf2f(src[lane]);
      float s = redsum64(val);
      float sq = redsum64(val * val);
      float mean = s * (1.f / 64.f);
      float var = sq * (1.f / 64.f) - mean * mean;
      float ln = (val - mean) * rsqrtf(var + LN_EPS) * nw[lane] + nb[lane];
      if (tau == 0)      { size_t base = (size_t)bh * QPAD * AUG; Qa[base + lane] = f2bf(ln * QSCALE); Qa[base + 64 + lane] = 0; }
      else if (tau == 1) { size_t base = (size_t)bh * NPAD * AUG; Ka[base + lane] = f2bf(ln); Ka[base + 64 + lane] = 0; }
      else               { Vt[((size_t)bh * HD + lane) * NPAD] = f2bf(ln); }
    } else {
      // pad rows -> zero (Qa to QPAD, Ka/Vt to NPAD)
      int lim = (tau == 0) ? QPAD : NPAD;
      for (int n = 1569 + (wv - 1); n < lim; n += 3) {
        if (tau == 0) {
          size_t base = ((size_t)bh * QPAD + n) * AUG;
          Qa[base + lane] = 0; Qa[base + 64 + lane] = 0;
        } else if (tau == 1) {
          size_t base = ((size_t)bh * NPAD + n) * AUG;
          Ka[base + lane] = 0; Ka[base + 64 + lane] = 0;
        } else {
          Vt[((size_t)bh * HD + lane) * NPAD + n] = 0;
        }
      }
    }
    return;
  }

  const int th = unit * 4 + wv;          // 0..111
  const int t = th / 14, hh = th % 14;

  float wt[27];
  {
    const float* wp = (tau == 0 ? pw_q : tau == 1 ? pw_k : pw_v) + lane * 27;
#pragma unroll
    for (int j = 0; j < 27; ++j) wt[j] = wp[j];
  }

  // per-row source offsets (loop-invariant); invalid rows -> zero page
  int roff[9];
#pragma unroll
  for (int dt = 0; dt < 3; ++dt)
#pragma unroll
    for (int dh = 0; dh < 3; ++dh) {
      int tt = t + dt - 1, h2 = hh + dh - 1;
      bool ok = ((unsigned)tt < 8u) && ((unsigned)h2 < 14u);
      roff[dt * 3 + dh] = (ok ? (1 + (tt * 14 + h2) * 14) * HD : zoff) + lane;
    }

  float win[9][3];
#pragma unroll
  for (int i = 0; i < 9; ++i) {
    win[i][0] = 0.f;
    win[i][1] = bf2f(src[roff[i]]);
    win[i][2] = bf2f(src[roff[i] + HD]);
  }

#pragma unroll
  for (int ww = 0; ww < 14; ++ww) {
    // prefetch next column (compile-time w-edge check; zero page rows load 0)
    float nxt[9];
#pragma unroll
    for (int i = 0; i < 9; ++i)
      nxt[i] = (ww + 2 < 14) ? bf2f(src[roff[i] + (ww + 2) * HD]) : 0.f;

    float a = 0.f;
#pragma unroll
    for (int i = 0; i < 9; ++i)
      a += win[i][0] * wt[i * 3 + 0] + win[i][1] * wt[i * 3 + 1] + win[i][2] * wt[i * 3 + 2];

    float s = redsum64(a);
    float sq = redsum64(a * a);
    float mean = s * (1.f / 64.f);
    float var = sq * (1.f / 64.f) - mean * mean;
    float ln = (a - mean) * rsqrtf(var + LN_EPS) * nw[lane] + nb[lane];

    const int n = 1 + (t * 14 + hh) * 14 + ww;
    if (tau == 0) {
      size_t base = ((size_t)bh * QPAD + n) * AUG;
      Qa[base + lane] = f2bf(ln * QSCALE);
      Qa[base + 64 + lane] = 0;  // k_rel fills lanes 64..99
    } else if (tau == 1) {
      size_t base = ((size_t)bh * NPAD + n) * AUG;
      Ka[base + lane] = f2bf(ln);
      u16 e = 0;
      if (lane == t || lane == 8 + hh || lane == 22 + ww) e = 0x3F80;  // bf16 1.0
      Ka[base + 64 + lane] = e;
    } else {
      Vt[((size_t)bh * HD + lane) * NPAD + n] = f2bf(ln);
    }

#pragma unroll
    for (int i = 0; i < 9; ++i) { win[i][0] = win[i][1]; win[i][1] = win[i][2]; win[i][2] = nxt[i]; }
  }
}

// ---------------- rel-pos dot table via MFMA ----------------
__global__ __launch_bounds__(256) void k_rel(const float* __restrict__ rel_t,
                                             const float* __restrict__ rel_h,
                                             const float* __restrict__ rel_w,
                                             u16* __restrict__ Qa) {
  __shared__ __align__(16) u16 sR[80 * 72];
  const int tid = threadIdx.x, w = tid >> 6, lane = tid & 63;
  const int g = lane >> 4, lr = lane & 15;
  const int bh = blockIdx.x / 25, qt = blockIdx.x % 25;

  for (int idx = tid; idx < 80 * 64; idx += 256) {
    int j = idx >> 6, c = idx & 63;
    float v = 0.f;
    if (j < 15)      v = rel_t[j * HD + c];
    else if (j < 42) v = rel_h[(j - 15) * HD + c];
    else if (j < 69) v = rel_w[(j - 42) * HD + c];
    sR[j * 72 + c] = f2bf(v * 8.f);
  }
  __syncthreads();

  const int q0 = qt * 64 + w * 16;
  short8 aq[2];
  {
    const u16* qrow = Qa + ((size_t)bh * QPAD + q0 + lr) * AUG;
    aq[0] = *(const short8*)(qrow + g * 8);
    aq[1] = *(const short8*)(qrow + 32 + g * 8);
  }

  f32x4 acc[5];
#pragma unroll
  for (int jt = 0; jt < 5; ++jt) {
    f32x4 a; a.x = 0.f; a.y = 0.f; a.z = 0.f; a.w = 0.f;
    int row = jt * 16 + lr;
    short8 b0 = *(const short8*)&sR[row * 72 + g * 8];
    short8 b1 = *(const short8*)&sR[row * 72 + (4 + g) * 8];
    a = __builtin_amdgcn_mfma_f32_16x16x32_bf16(aq[0], b0, a, 0, 0, 0);
    a = __builtin_amdgcn_mfma_f32_16x16x32_bf16(aq[1], b1, a, 0, 0, 0);
    acc[jt] = a;
  }

#pragma unroll
  for (int jt = 0; jt < 5; ++jt) {
    int j = jt * 16 + lr;
#pragma unroll
    for (int r = 0; r < 4; ++r) {
      int gq = q0 + g * 4 + r;
      if (gq < 1 || gq >= NTOK) continue;
      int p = gq - 1;
      int t = p / 196, pr = p - t * 196;
      int hh = pr / 14, ww = pr - hh * 14;
      int it = t + 7 - j;
      int ih = hh + 28 - j;
      int iw = ww + 55 - j;
      int i = -1;
      if ((unsigned)it < 8u) i = it;
      else if ((unsigned)ih < 14u) i = 8 + ih;
      else if ((unsigned)iw < 14u) i = 22 + iw;
      if (i >= 0)
        Qa[((size_t)bh * QPAD + gq) * AUG + 64 + i] = f2bf(acc[jt][r]);
    }
  }
}

// ---------------- fused flash attention (KV-split x2, swapped QK, no max-tracking) ----------------
__global__ __launch_bounds__(256, 3) void k_attn(const u16* __restrict__ Qa,
                                                 const u16* __restrict__ Ka,
                                                 const u16* __restrict__ Vt,
                                                 u16* __restrict__ Opart,
                                                 float* __restrict__ lsum) {
  __shared__ __align__(16) u16 sK[64 * 128];     // K_aug tile, single-buffered
  __shared__ __align__(16) u16 sV[2][64 * 64];   // V^T tile, double-buffered
  __shared__ __align__(16) u16 sP[4][32 * 72];   // per-wave P [q][key], stride 72
  const int tid = threadIdx.x, w = tid >> 6, lane = tid & 63;
  const int g = lane >> 4, lr = lane & 15;
  const int bid = blockIdx.x;
  const int swz = (bid & 7) * 156 + (bid >> 3);  // XCD-chunked (1248 = 8*156)
  const int bh = swz / 26, rem2 = swz % 26;
  const int half = rem2 / 13, qt = rem2 % 13;
  const int qw = qt * 128 + w * 32;
  const int kb0 = half * 13;
  const int kbN = half ? 12 : 13;

  short8 aq[2][4];
#pragma unroll
  for (int f = 0; f < 2; ++f) {
    const u16* qrow = Qa + ((size_t)bh * QPAD + qw + f * 16 + lr) * AUG;
#pragma unroll
    for (int ks = 0; ks < 4; ++ks) aq[f][ks] = *(const short8*)(qrow + ks * 32 + g * 8);
  }

  short8 vones;
#pragma unroll
  for (int i = 0; i < 8; ++i) vones[i] = (short)0x3F80;

  const u16* kgp[4];
  u16* kld[4];
#pragma unroll
  for (int j = 0; j < 4; ++j) {
    int idx = j * 256 + tid;
    int row = idx >> 4, ch = idx & 15;
    int gch = ch ^ (row & 7);
    kgp[j] = Ka + ((size_t)bh * NPAD + kb0 * 64 + row) * AUG + gch * 8;
    kld[j] = &sK[(j * 256 + w * 64) * 8];
  }
  const u16* vgp[2];
  int vld[2];
#pragma unroll
  for (int j = 0; j < 2; ++j) {
    int idx = j * 256 + tid;
    int row = idx >> 3, ch = idx & 7;
    int gch = ch ^ (row & 7);
    vgp[j] = Vt + ((size_t)bh * HD + row) * NPAD + kb0 * 64 + gch * 8;
    vld[j] = (j * 256 + w * 64) * 8;
  }

#pragma unroll
  for (int j = 0; j < 4; ++j) { gld16(kgp[j], kld[j]); kgp[j] += 64 * AUG; }
#pragma unroll
  for (int j = 0; j < 2; ++j) { gld16(vgp[j], &sV[0][vld[j]]); vgp[j] += 64; }
  __syncthreads();

  f32x4 O[2][5];
#pragma unroll
  for (int f = 0; f < 2; ++f)
#pragma unroll
    for (int c4 = 0; c4 < 5; ++c4) { O[f][c4].x = 0.f; O[f][c4].y = 0.f; O[f][c4].z = 0.f; O[f][c4].w = 0.f; }

  int cur = 0;
  for (int it = 0; it < kbN; ++it) {
    // ---- S^T = K * Q^T (swapped: D row = key = g*4+r, col = q = lr) ----
    f32x4 sacc[2][4];
    __builtin_amdgcn_s_setprio(1);
#pragma unroll
    for (int ct = 0; ct < 4; ++ct) {
      int row = ct * 16 + lr;
      int sw = row & 7;
      short8 bk[4];
#pragma unroll
      for (int ks = 0; ks < 4; ++ks)
        bk[ks] = *(const short8*)&sK[row * 128 + (((ks * 4 + g) ^ sw) << 3)];
#pragma unroll
      for (int f = 0; f < 2; ++f) {
        f32x4 a; a.x = 0.f; a.y = 0.f; a.z = 0.f; a.w = 0.f;
#pragma unroll
        for (int ks = 0; ks < 4; ++ks)
          a = __builtin_amdgcn_mfma_f32_16x16x32_bf16(bk[ks], aq[f][ks], a, 0, 0, 0);
        sacc[f][ct] = a;
      }
    }
    __builtin_amdgcn_s_setprio(0);
    __syncthreads();  // barrier A: all QK reads of sK done

    if (it + 1 < kbN) {
#pragma unroll
      for (int j = 0; j < 4; ++j) { gld16(kgp[j], kld[j]); kgp[j] += 64 * AUG; }
#pragma unroll
      for (int j = 0; j < 2; ++j) { gld16(vgp[j], &sV[cur ^ 1][vld[j]]); vgp[j] += 64; }
    }

    if (kb0 + it == 24) {  // tail: local keys >= 33 invalid (key = ct*16+g*4+r)
#pragma unroll
      for (int f = 0; f < 2; ++f) {
        sacc[f][2][0] = (g == 0) ? sacc[f][2][0] : -1e30f;
        sacc[f][2][1] = -1e30f; sacc[f][2][2] = -1e30f; sacc[f][2][3] = -1e30f;
        sacc[f][3][0] = -1e30f; sacc[f][3][1] = -1e30f;
        sacc[f][3][2] = -1e30f; sacc[f][3][3] = -1e30f;
      }
    }

    // ---- P = exp2(S), pack 4 consecutive keys -> b64 LDS write ----
#pragma unroll
    for (int f = 0; f < 2; ++f) {
      int ro = (f * 16 + lr) * 72;
#pragma unroll
      for (int ct = 0; ct < 4; ++ct) {
        unsigned u0 = __float_as_uint(exp2f(sacc[f][ct][0]));
        unsigned u1 = __float_as_uint(exp2f(sacc[f][ct][1]));
        unsigned u2 = __float_as_uint(exp2f(sacc[f][ct][2]));
        unsigned u3 = __float_as_uint(exp2f(sacc[f][ct][3]));
        uint2 pk;
        pk.x = __builtin_amdgcn_perm(u1, u0, 0x07060302u);
        pk.y = __builtin_amdgcn_perm(u3, u2, 0x07060302u);
        *(uint2*)&sP[w][ro + ct * 16 + g * 4] = pk;
      }
    }

    // ---- O += P * V^T (c4=4 vs ones-frag accumulates l) ----
    __builtin_amdgcn_s_setprio(1);
#pragma unroll
    for (int kk = 0; kk < 2; ++kk) {
      short8 ap[2];
#pragma unroll
      for (int f = 0; f < 2; ++f)
        ap[f] = *(const short8*)&sP[w][(f * 16 + lr) * 72 + kk * 32 + g * 8];
#pragma unroll
      for (int c4 = 0; c4 < 4; ++c4) {
        int row = c4 * 16 + lr;
        int sw = row & 7;
        short8 bv = *(const short8*)&sV[cur][row * 64 + (((kk * 4 + g) ^ sw) << 3)];
#pragma unroll
        for (int f = 0; f < 2; ++f)
          O[f][c4] = __builtin_amdgcn_mfma_f32_16x16x32_bf16(ap[f], bv, O[f][c4], 0, 0, 0);
      }
#pragma unroll
      for (int f = 0; f < 2; ++f)
        O[f][4] = __builtin_amdgcn_mfma_f32_16x16x32_bf16(ap[f], vones, O[f][4], 0, 0, 0);
    }
    __builtin_amdgcn_s_setprio(0);

    __syncthreads();  // barrier B
    cur ^= 1;
  }

  size_t pbase = (size_t)(bh * 2 + half) * QPAD;
#pragma unroll
  for (int f = 0; f < 2; ++f)
#pragma unroll
    for (int r = 0; r < 4; ++r) {
      int qg = qw + f * 16 + g * 4 + r;
      if (qg >= NTOK) continue;
      float l = O[f][4][r];
      float inv = 1.f / l;
#pragma unroll
      for (int c4 = 0; c4 < 4; ++c4)
        Opart[(pbase + qg) * 64 + c4 * 16 + lr] = f2bf(O[f][c4][r] * inv);
      if (lr == 0) lsum[pbase + qg] = l;
    }
}

// ---------------- combine halves + residual (pure l-weighting) ----------------
__global__ __launch_bounds__(256) void k_comb(const u16* __restrict__ Opart,
                                              const float* __restrict__ lsum,
                                              const u16* __restrict__ Qa,
                                              u16* __restrict__ outA) {
  const int wv = threadIdx.x >> 6, lane = threadIdx.x & 63;
  int rid = blockIdx.x * 4 + wv;
  if (rid >= BHN * NTOK) return;
  int bh = rid / NTOK, qg = rid - bh * NTOK;
  size_t base0 = (size_t)(bh * 2) * QPAD + qg;
  size_t base1 = base0 + QPAD;
  float l0 = lsum[base0], l1 = lsum[base1];
  float inv = 1.f / (l0 + l1);
  float o0 = bf2f(Opart[base0 * 64 + lane]);
  float o1 = bf2f(Opart[base1 * 64 + lane]);
  float v = (l0 * o0 + l1 * o1) * inv;
  if (qg >= 1) v += RESID * bf2f(Qa[((size_t)bh * QPAD + qg) * AUG + lane]);
  int b = bh / HEADS, h = bh - b * HEADS;
  outA[((size_t)(b * NTOK + qg)) * DIM + h * HD + lane] = f2bf(v);
}

// ---------------- launch ----------------
extern "C" void kernel_launch(void* const* d_in, const int* in_sizes, int n_in,
                              void* d_out, int out_size, void* d_ws, size_t ws_size,
                              hipStream_t stream) {
  (void)in_sizes; (void)n_in; (void)out_size; (void)ws_size;
  const float* x      = (const float*)d_in[0];
  const float* qkv_w  = (const float*)d_in[1];
  const float* qkv_b  = (const float*)d_in[2];
  const float* proj_w = (const float*)d_in[3];
  const float* proj_b = (const float*)d_in[4];
  const float* pw_q   = (const float*)d_in[5];
  const float* pw_k   = (const float*)d_in[6];
  const float* pw_v   = (const float*)d_in[7];
  const float* nw_q   = (const float*)d_in[8];
  const float* nb_q   = (const float*)d_in[9];
  const float* nw_k   = (const float*)d_in[10];
  const float* nb_k   = (const float*)d_in[11];
  const float* nw_v   = (const float*)d_in[12];
  const float* nb_v   = (const float*)d_in[13];
  const float* rel_t  = (const float*)d_in[14];
  const float* rel_h  = (const float*)d_in[15];
  const float* rel_w  = (const float*)d_in[16];
  float* out = (float*)d_out;

  char* ws = (char*)d_ws;
  size_t off = 0;
  auto alloc = [&](size_t bytes) -> void* {
    off = (off + 511) & ~(size_t)511;
    void* p = ws + off;
    off += bytes;
    return p;
  };
  u16*   xb     = (u16*)alloc((size_t)MP * DIM * 2);
  u16*   qkvwT  = (u16*)alloc((size_t)DIM3 * DIM * 2);
  u16*   projwT = (u16*)alloc((size_t)DIM * DIM * 2);
  u16*   qkvf   = (u16*)alloc((size_t)3 * BHN * SLAB * 2 + 2048);  // + zero page
  u16*   Qa     = (u16*)alloc((size_t)BHN * QPAD * AUG * 2);
  u16*   Ka     = (u16*)alloc((size_t)BHN * NPAD * AUG * 2);
  u16*   Vt     = (u16*)alloc((size_t)BHN * HD * NPAD * 2);
  u16*   attnO  = (u16*)alloc((size_t)MP * DIM * 2);
  u16*   Opart  = (u16*)alloc((size_t)BHN * 2 * QPAD * HD * 2);
  float* lbuf   = (float*)alloc((size_t)BHN * 2 * QPAD * 4);

  // zero page (1024 bf16) read by k_pool's out-of-range conv rows
  hipMemsetAsync(qkvf + (size_t)3 * BHN * SLAB, 0, 2048, stream);

  k_cast_x<<<dim3(MP * DIM / 1024), dim3(256), 0, stream>>>(x, xb);
  k_transpose_cast<<<dim3((DIM3 / 32) * (DIM / 32)), dim3(256), 0, stream>>>(qkv_w, qkvwT, DIM, DIM3);
  k_transpose_cast<<<dim3((DIM / 32) * (DIM / 32)), dim3(256), 0, stream>>>(proj_w, projwT, DIM, DIM);

  k_gemm<0><<<dim3(MP / 128, DIM3 / 128), dim3(256), 0, stream>>>(xb, qkvwT, qkv_b, qkvf);

  k_pool<<<dim3(3 * BHN * 29), dim3(256), 0, stream>>>(
      qkvf, pw_q, pw_k, pw_v, nw_q, nb_q, nw_k, nb_k, nw_v, nb_v,
      Qa, Ka, Vt);

  k_rel<<<dim3(BHN * 25), dim3(256), 0, stream>>>(rel_t, rel_h, rel_w, Qa);

  k_attn<<<dim3(BHN * 26), dim3(256), 0, stream>>>(Qa, Ka, Vt, Opart, lbuf);

  k_comb<<<dim3((BHN * NTOK + 3) / 4), dim3(256), 0, stream>>>(Opart, lbuf, Qa, attnO);

  k_gemm<1><<<dim3(MP / 128, DIM / 128), dim3(256), 0, stream>>>(attnO, projwT, proj_b, out);
}

// Round 8
// 244.533 us; speedup vs baseline: 1.2077x; 1.2077x over previous
//
#include <hip/hip_runtime.h>
#include <cstdint>
#include <cstddef>

typedef __attribute__((ext_vector_type(8))) short short8;
typedef __attribute__((ext_vector_type(4))) short short4v;
typedef __attribute__((ext_vector_type(4))) float f32x4;
typedef unsigned short u16;

#define DI __device__ __forceinline__

// ---------------- problem constants ----------------
constexpr int BATCH = 4;
constexpr int HEADS = 12, HD = 64;
constexpr int NTOK = 1569;          // T*H*W + 1
constexpr int NPAD = 1600;          // kv pad (25*64), qkvf row pad
constexpr int QPAD = 1664;          // q pad (13*128)
constexpr int DIM = 768, DIM3 = 2304;
constexpr int MROWS = BATCH * NTOK; // 6276
constexpr int MP = 6400;            // 50 * 128
constexpr int AUG = 128;            // 64 ch + 8 + 14 + 14 + pad
constexpr int BHN = BATCH * HEADS;  // 48
constexpr float LOG2E = 1.4426950408889634f;
constexpr float QSCALE = 0.125f * LOG2E;  // attn scale folded with log2e (exp2 domain)
constexpr float RESID = 8.0f / LOG2E;     // 1/QSCALE
constexpr float LN_EPS = 1e-5f;
constexpr int SLAB = NPAD * HD;           // 102400 elems per (tau,bh) slab

// ---------------- helpers ----------------
DI u16 f2bf(float x) {
  union { float f; unsigned u; } v; v.f = x;
  unsigned r = v.u + 0x7FFFu + ((v.u >> 16) & 1u);
  return (u16)(r >> 16);
}
DI float bf2f(u16 h) {
  union { unsigned u; float f; } v; v.u = ((unsigned)h) << 16;
  return v.f;
}

typedef const __attribute__((address_space(1))) unsigned int gu32;
typedef __attribute__((address_space(3))) unsigned int lu32;
DI void gld16(const void* g, void* l) {
  __builtin_amdgcn_global_load_lds((gu32*)g, (lu32*)l, 16, 0, 0);
}

// full 64-lane sum: 4 DPP row_ror levels (VALU pipe) + xor16/xor32 cross-row
DI float redsum64(float x) {
  int t;
  t = __builtin_amdgcn_update_dpp(__float_as_int(x), __float_as_int(x), 0x121, 0xF, 0xF, false);
  x += __int_as_float(t);
  t = __builtin_amdgcn_update_dpp(__float_as_int(x), __float_as_int(x), 0x122, 0xF, 0xF, false);
  x += __int_as_float(t);
  t = __builtin_amdgcn_update_dpp(__float_as_int(x), __float_as_int(x), 0x124, 0xF, 0xF, false);
  x += __int_as_float(t);
  t = __builtin_amdgcn_update_dpp(__float_as_int(x), __float_as_int(x), 0x128, 0xF, 0xF, false);
  x += __int_as_float(t);
  x += __shfl_xor(x, 16);
  x += __shfl_xor(x, 32);
  return x;
}

// ---------------- cast / prep kernels ----------------
__global__ __launch_bounds__(256) void k_cast_x(const float* __restrict__ x,
                                                u16* __restrict__ xb) {
  int i = (blockIdx.x * 256 + threadIdx.x) * 4;
  if (i >= MP * DIM) return;
  int row = i / DIM;
  short4v o;
  if (row < MROWS) {
    float4 v = *(const float4*)(x + i);
    o.x = (short)f2bf(v.x); o.y = (short)f2bf(v.y);
    o.z = (short)f2bf(v.z); o.w = (short)f2bf(v.w);
  } else {
    o.x = 0; o.y = 0; o.z = 0; o.w = 0;
  }
  *(short4v*)(xb + i) = o;
}

// transpose depthwise conv weights (HD,27) -> (tau,27,HD) for coalesced loads
__global__ __launch_bounds__(256) void k_prep(const float* __restrict__ pq,
                                              const float* __restrict__ pk,
                                              const float* __restrict__ pv,
                                              float* __restrict__ pwT) {
  int i = blockIdx.x * 256 + threadIdx.x;
  if (i >= 3 * 27 * 64) return;
  int tau = i / (27 * 64), r = i % (27 * 64);
  int tap = r >> 6, c = r & 63;
  const float* src = tau == 0 ? pq : tau == 1 ? pk : pv;
  pwT[i] = src[c * 27 + tap];
}

// dst (NC, K) bf16 = transpose of src (K, NC) f32 — LDS 32x32 tile transpose
__global__ __launch_bounds__(256) void k_transpose_cast(const float* __restrict__ src,
                                                        u16* __restrict__ dst,
                                                        int K, int NC) {
  __shared__ float tile[32][33];
  const int ntiles = NC >> 5;
  const int bx = blockIdx.x % ntiles;  // n-tile
  const int by = blockIdx.x / ntiles;  // k-tile
  const int tx = threadIdx.x & 31, ty = threadIdx.x >> 5;
  const int n0 = bx * 32, k0 = by * 32;
#pragma unroll
  for (int r = 0; r < 32; r += 8)
    tile[ty + r][tx] = src[(size_t)(k0 + ty + r) * NC + n0 + tx];
  __syncthreads();
#pragma unroll
  for (int r = 0; r < 32; r += 8)
    dst[(size_t)(n0 + ty + r) * K + k0 + tx] = f2bf(tile[tx][ty + r]);
}

// ---------------- GEMM: C(M,N) = A(M,768)*Bt(N,768)^T + bias ----------------
// EPI 0: scatter bf16 to qkv ws (t,b,h,n,c).  EPI 1: linear f32 out (proj).
template <int EPI>
__global__ __launch_bounds__(256) void k_gemm(const u16* __restrict__ A,
                                              const u16* __restrict__ Bt,
                                              const float* __restrict__ bias,
                                              void* __restrict__ outv) {
  __shared__ __align__(16) u16 sA[128 * 64];
  __shared__ __align__(16) u16 sB[128 * 64];
  const int tid = threadIdx.x;
  const int w = tid >> 6, lane = tid & 63;
  const int g = lane >> 4, lr = lane & 15;
  const int brow = blockIdx.x * 128, bcol = blockIdx.y * 128;
  const int wr = w >> 1, wc = w & 1;

  f32x4 acc[4][4];
#pragma unroll
  for (int m = 0; m < 4; ++m)
#pragma unroll
    for (int n = 0; n < 4; ++n) {
      acc[m][n].x = 0.f; acc[m][n].y = 0.f; acc[m][n].z = 0.f; acc[m][n].w = 0.f;
    }

  for (int kt = 0; kt < 12; ++kt) {
    __syncthreads();
#pragma unroll
    for (int j = 0; j < 4; ++j) {
      int cb = (j * 4 + w) * 64;
      int chunk = cb + lane;
      int row = chunk >> 3, ch = chunk & 7;
      int gch = ch ^ (row & 7);
      gld16(A + (size_t)(brow + row) * DIM + kt * 64 + gch * 8, &sA[cb * 8]);
      gld16(Bt + (size_t)(bcol + row) * DIM + kt * 64 + gch * 8, &sB[cb * 8]);
    }
    __syncthreads();

    short8 af[4][2], bfr[4][2];
#pragma unroll
    for (int m = 0; m < 4; ++m) {
      int row = wr * 64 + m * 16 + lr;
      int sw = row & 7;
#pragma unroll
      for (int ks = 0; ks < 2; ++ks)
        af[m][ks] = *(const short8*)&sA[row * 64 + (((ks * 4 + g) ^ sw) * 8)];
    }
#pragma unroll
    for (int n = 0; n < 4; ++n) {
      int row = wc * 64 + n * 16 + lr;
      int sw = row & 7;
#pragma unroll
      for (int ks = 0; ks < 2; ++ks)
        bfr[n][ks] = *(const short8*)&sB[row * 64 + (((ks * 4 + g) ^ sw) * 8)];
    }
#pragma unroll
    for (int m = 0; m < 4; ++m)
#pragma unroll
      for (int n = 0; n < 4; ++n) {
        acc[m][n] = __builtin_amdgcn_mfma_f32_16x16x32_bf16(af[m][0], bfr[n][0], acc[m][n], 0, 0, 0);
        acc[m][n] = __builtin_amdgcn_mfma_f32_16x16x32_bf16(af[m][1], bfr[n][1], acc[m][n], 0, 0, 0);
      }
  }

#pragma unroll
  for (int m = 0; m < 4; ++m)
#pragma unroll
    for (int n = 0; n < 4; ++n) {
      int gj = bcol + wc * 64 + n * 16 + lr;
      float bv = bias[gj];
#pragma unroll
      for (int r = 0; r < 4; ++r) {
        int gm = brow + wr * 64 + m * 16 + g * 4 + r;
        if (gm >= MROWS) continue;
        float v = acc[m][n][r] + bv;
        if (EPI == 0) {
          int t = gj >= 1536 ? 2 : (gj >= 768 ? 1 : 0);
          int rem = gj - t * 768;
          int h = rem >> 6, c = rem & 63;
          int b = gm >= 3 * NTOK ? 3 : (gm >= 2 * NTOK ? 2 : (gm >= NTOK ? 1 : 0));
          int nt = gm - b * NTOK;
          ((u16*)outv)[(((size_t)(t * BATCH + b) * HEADS + h) * NPAD + nt) * HD + c] = f2bf(v);
        } else {
          ((float*)outv)[(size_t)gm * DIM + gj] = v;
        }
      }
    }
}

// ---------------- pool (depthwise conv3d) + LN + aug writes ----------------
// Wave = one (tau, bh, t, h) row; slides 3x3x3 window along w. bf16 input,
// zero-page redirect for out-of-range rows, coalesced transposed weights.
__global__ __launch_bounds__(256, 4) void k_pool(
    const u16* __restrict__ qkv,   // bf16 slabs + zero page at end
    const float* __restrict__ pwT, // (tau,27,64) transposed conv weights
    const float* __restrict__ nw_q, const float* __restrict__ nb_q,
    const float* __restrict__ nw_k, const float* __restrict__ nb_k,
    const float* __restrict__ nw_v, const float* __restrict__ nb_v,
    u16* __restrict__ Qa, u16* __restrict__ Ka, u16* __restrict__ Vt) {
  const int wv = threadIdx.x >> 6, lane = threadIdx.x & 63;
  const int unit = blockIdx.x % 29;
  const int taubh = blockIdx.x / 29;
  const int tau = taubh / BHN, bh = taubh % BHN;
  const u16* src = qkv + (size_t)taubh * SLAB;
  const int zoff = (3 * BHN - taubh) * SLAB;   // zero page offset from src (elems)
  const float* nw = tau == 0 ? nw_q : tau == 1 ? nw_k : nw_v;
  const float* nb = tau == 0 ? nb_q : tau == 1 ? nb_k : nb_v;

  if (unit == 28) {
    if (wv == 0) {
      // CLS token (n = 0)
      float val = bf2f(src[lane]);
      float s = redsum64(val);
      float sq = redsum64(val * val);
      float mean = s * (1.f / 64.f);
      float var = sq * (1.f / 64.f) - mean * mean;
      float ln = (val - mean) * rsqrtf(var + LN_EPS) * nw[lane] + nb[lane];
      if (tau == 0)      { size_t base = (size_t)bh * QPAD * AUG; Qa[base + lane] = f2bf(ln * QSCALE); Qa[base + 64 + lane] = 0; }
      else if (tau == 1) { size_t base = (size_t)bh * NPAD * AUG; Ka[base + lane] = f2bf(ln); Ka[base + 64 + lane] = 0; }
      else               { Vt[((size_t)bh * HD + lane) * NPAD] = f2bf(ln); }
    } else {
      // pad rows -> zero (Qa to QPAD, Ka/Vt to NPAD)
      int lim = (tau == 0) ? QPAD : NPAD;
      for (int n = 1569 + (wv - 1); n < lim; n += 3) {
        if (tau == 0) {
          size_t base = ((size_t)bh * QPAD + n) * AUG;
          Qa[base + lane] = 0; Qa[base + 64 + lane] = 0;
        } else if (tau == 1) {
          size_t base = ((size_t)bh * NPAD + n) * AUG;
          Ka[base + lane] = 0; Ka[base + 64 + lane] = 0;
        } else {
          Vt[((size_t)bh * HD + lane) * NPAD + n] = 0;
        }
      }
    }
    return;
  }

  const int th = unit * 4 + wv;          // 0..111
  const int t = th / 14, hh = th % 14;

  // coalesced weight load from transposed table (27 x 256B contiguous)
  float wt[27];
  {
    const float* wp = pwT + tau * 27 * 64 + lane;
#pragma unroll
    for (int j = 0; j < 27; ++j) wt[j] = wp[j * 64];
  }

  // per-row source offsets (loop-invariant); invalid rows -> zero page
  int roff[9];
#pragma unroll
  for (int dt = 0; dt < 3; ++dt)
#pragma unroll
    for (int dh = 0; dh < 3; ++dh) {
      int tt = t + dt - 1, h2 = hh + dh - 1;
      bool ok = ((unsigned)tt < 8u) && ((unsigned)h2 < 14u);
      roff[dt * 3 + dh] = (ok ? (1 + (tt * 14 + h2) * 14) * HD : zoff) + lane;
    }

  float win[9][3];
#pragma unroll
  for (int i = 0; i < 9; ++i) {
    win[i][0] = 0.f;
    win[i][1] = bf2f(src[roff[i]]);
    win[i][2] = bf2f(src[roff[i] + HD]);
  }

#pragma unroll
  for (int ww = 0; ww < 14; ++ww) {
    // prefetch next column (compile-time w-edge check; zero page rows load 0)
    float nxt[9];
#pragma unroll
    for (int i = 0; i < 9; ++i)
      nxt[i] = (ww + 2 < 14) ? bf2f(src[roff[i] + (ww + 2) * HD]) : 0.f;

    // conv with 3-way accumulator tree (shorter dependent chain)
    float a0 = 0.f, a1 = 0.f, a2 = 0.f;
#pragma unroll
    for (int i = 0; i < 9; i += 3) {
      a0 += win[i][0] * wt[i * 3 + 0] + win[i][1] * wt[i * 3 + 1] + win[i][2] * wt[i * 3 + 2];
      a1 += win[i + 1][0] * wt[i * 3 + 3] + win[i + 1][1] * wt[i * 3 + 4] + win[i + 1][2] * wt[i * 3 + 5];
      a2 += win[i + 2][0] * wt[i * 3 + 6] + win[i + 2][1] * wt[i * 3 + 7] + win[i + 2][2] * wt[i * 3 + 8];
    }
    float a = (a0 + a1) + a2;

    float s = redsum64(a);
    float sq = redsum64(a * a);
    float mean = s * (1.f / 64.f);
    float var = sq * (1.f / 64.f) - mean * mean;
    float ln = (a - mean) * rsqrtf(var + LN_EPS) * nw[lane] + nb[lane];

    const int n = 1 + (t * 14 + hh) * 14 + ww;
    if (tau == 0) {
      size_t base = ((size_t)bh * QPAD + n) * AUG;
      Qa[base + lane] = f2bf(ln * QSCALE);
      Qa[base + 64 + lane] = 0;  // k_rel fills lanes 64..99
    } else if (tau == 1) {
      size_t base = ((size_t)bh * NPAD + n) * AUG;
      Ka[base + lane] = f2bf(ln);
      u16 e = 0;
      if (lane == t || lane == 8 + hh || lane == 22 + ww) e = 0x3F80;  // bf16 1.0
      Ka[base + 64 + lane] = e;
    } else {
      Vt[((size_t)bh * HD + lane) * NPAD + n] = f2bf(ln);
    }

#pragma unroll
    for (int i = 0; i < 9; ++i) { win[i][0] = win[i][1]; win[i][1] = win[i][2]; win[i][2] = nxt[i]; }
  }
}

// ---------------- rel-pos dot table via MFMA ----------------
__global__ __launch_bounds__(256) void k_rel(const float* __restrict__ rel_t,
                                             const float* __restrict__ rel_h,
                                             const float* __restrict__ rel_w,
                                             u16* __restrict__ Qa) {
  __shared__ __align__(16) u16 sR[80 * 72];
  const int tid = threadIdx.x, w = tid >> 6, lane = tid & 63;
  const int g = lane >> 4, lr = lane & 15;
  const int bh = blockIdx.x / 25, qt = blockIdx.x % 25;

  for (int idx = tid; idx < 80 * 64; idx += 256) {
    int j = idx >> 6, c = idx & 63;
    float v = 0.f;
    if (j < 15)      v = rel_t[j * HD + c];
    else if (j < 42) v = rel_h[(j - 15) * HD + c];
    else if (j < 69) v = rel_w[(j - 42) * HD + c];
    sR[j * 72 + c] = f2bf(v * 8.f);
  }
  __syncthreads();

  const int q0 = qt * 64 + w * 16;
  short8 aq[2];
  {
    const u16* qrow = Qa + ((size_t)bh * QPAD + q0 + lr) * AUG;
    aq[0] = *(const short8*)(qrow + g * 8);
    aq[1] = *(const short8*)(qrow + 32 + g * 8);
  }

  f32x4 acc[5];
#pragma unroll
  for (int jt = 0; jt < 5; ++jt) {
    f32x4 a; a.x = 0.f; a.y = 0.f; a.z = 0.f; a.w = 0.f;
    int row = jt * 16 + lr;
    short8 b0 = *(const short8*)&sR[row * 72 + g * 8];
    short8 b1 = *(const short8*)&sR[row * 72 + (4 + g) * 8];
    a = __builtin_amdgcn_mfma_f32_16x16x32_bf16(aq[0], b0, a, 0, 0, 0);
    a = __builtin_amdgcn_mfma_f32_16x16x32_bf16(aq[1], b1, a, 0, 0, 0);
    acc[jt] = a;
  }

#pragma unroll
  for (int jt = 0; jt < 5; ++jt) {
    int j = jt * 16 + lr;
#pragma unroll
    for (int r = 0; r < 4; ++r) {
      int gq = q0 + g * 4 + r;
      if (gq < 1 || gq >= NTOK) continue;
      int p = gq - 1;
      int t = p / 196, pr = p - t * 196;
      int hh = pr / 14, ww = pr - hh * 14;
      int it = t + 7 - j;
      int ih = hh + 28 - j;
      int iw = ww + 55 - j;
      int i = -1;
      if ((unsigned)it < 8u) i = it;
      else if ((unsigned)ih < 14u) i = 8 + ih;
      else if ((unsigned)iw < 14u) i = 22 + iw;
      if (i >= 0)
        Qa[((size_t)bh * QPAD + gq) * AUG + 64 + i] = f2bf(acc[jt][r]);
    }
  }
}

// ---------------- fused flash attention (KV-split x2, swapped QK, no max-tracking) ----------------
__global__ __launch_bounds__(256, 3) void k_attn(const u16* __restrict__ Qa,
                                                 const u16* __restrict__ Ka,
                                                 const u16* __restrict__ Vt,
                                                 u16* __restrict__ Opart,
                                                 float* __restrict__ lsum) {
  __shared__ __align__(16) u16 sK[64 * 128];     // K_aug tile, single-buffered
  __shared__ __align__(16) u16 sV[2][64 * 64];   // V^T tile, double-buffered
  __shared__ __align__(16) u16 sP[4][32 * 72];   // per-wave P [q][key], stride 72
  const int tid = threadIdx.x, w = tid >> 6, lane = tid & 63;
  const int g = lane >> 4, lr = lane & 15;
  const int bid = blockIdx.x;
  const int swz = (bid & 7) * 156 + (bid >> 3);  // XCD-chunked (1248 = 8*156)
  const int bh = swz / 26, rem2 = swz % 26;
  const int half = rem2 / 13, qt = rem2 % 13;
  const int qw = qt * 128 + w * 32;
  const int kb0 = half * 13;
  const int kbN = half ? 12 : 13;

  short8 aq[2][4];
#pragma unroll
  for (int f = 0; f < 2; ++f) {
    const u16* qrow = Qa + ((size_t)bh * QPAD + qw + f * 16 + lr) * AUG;
#pragma unroll
    for (int ks = 0; ks < 4; ++ks) aq[f][ks] = *(const short8*)(qrow + ks * 32 + g * 8);
  }

  short8 vones;
#pragma unroll
  for (int i = 0; i < 8; ++i) vones[i] = (short)0x3F80;

  const u16* kgp[4];
  u16* kld[4];
#pragma unroll
  for (int j = 0; j < 4; ++j) {
    int idx = j * 256 + tid;
    int row = idx >> 4, ch = idx & 15;
    int gch = ch ^ (row & 7);
    kgp[j] = Ka + ((size_t)bh * NPAD + kb0 * 64 + row) * AUG + gch * 8;
    kld[j] = &sK[(j * 256 + w * 64) * 8];
  }
  const u16* vgp[2];
  int vld[2];
#pragma unroll
  for (int j = 0; j < 2; ++j) {
    int idx = j * 256 + tid;
    int row = idx >> 3, ch = idx & 7;
    int gch = ch ^ (row & 7);
    vgp[j] = Vt + ((size_t)bh * HD + row) * NPAD + kb0 * 64 + gch * 8;
    vld[j] = (j * 256 + w * 64) * 8;
  }

#pragma unroll
  for (int j = 0; j < 4; ++j) { gld16(kgp[j], kld[j]); kgp[j] += 64 * AUG; }
#pragma unroll
  for (int j = 0; j < 2; ++j) { gld16(vgp[j], &sV[0][vld[j]]); vgp[j] += 64; }
  __syncthreads();

  f32x4 O[2][5];
#pragma unroll
  for (int f = 0; f < 2; ++f)
#pragma unroll
    for (int c4 = 0; c4 < 5; ++c4) { O[f][c4].x = 0.f; O[f][c4].y = 0.f; O[f][c4].z = 0.f; O[f][c4].w = 0.f; }

  int cur = 0;
  for (int it = 0; it < kbN; ++it) {
    // ---- S^T = K * Q^T (swapped: D row = key = g*4+r, col = q = lr) ----
    f32x4 sacc[2][4];
    __builtin_amdgcn_s_setprio(1);
#pragma unroll
    for (int ct = 0; ct < 4; ++ct) {
      int row = ct * 16 + lr;
      int sw = row & 7;
      short8 bk[4];
#pragma unroll
      for (int ks = 0; ks < 4; ++ks)
        bk[ks] = *(const short8*)&sK[row * 128 + (((ks * 4 + g) ^ sw) << 3)];
#pragma unroll
      for (int f = 0; f < 2; ++f) {
        f32x4 a; a.x = 0.f; a.y = 0.f; a.z = 0.f; a.w = 0.f;
#pragma unroll
        for (int ks = 0; ks < 4; ++ks)
          a = __builtin_amdgcn_mfma_f32_16x16x32_bf16(bk[ks], aq[f][ks], a, 0, 0, 0);
        sacc[f][ct] = a;
      }
    }
    __builtin_amdgcn_s_setprio(0);
    __syncthreads();  // barrier A: all QK reads of sK done

    if (it + 1 < kbN) {
#pragma unroll
      for (int j = 0; j < 4; ++j) { gld16(kgp[j], kld[j]); kgp[j] += 64 * AUG; }
#pragma unroll
      for (int j = 0; j < 2; ++j) { gld16(vgp[j], &sV[cur ^ 1][vld[j]]); vgp[j] += 64; }
    }

    if (kb0 + it == 24) {  // tail: local keys >= 33 invalid (key = ct*16+g*4+r)
#pragma unroll
      for (int f = 0; f < 2; ++f) {
        sacc[f][2][0] = (g == 0) ? sacc[f][2][0] : -1e30f;
        sacc[f][2][1] = -1e30f; sacc[f][2][2] = -1e30f; sacc[f][2][3] = -1e30f;
        sacc[f][3][0] = -1e30f; sacc[f][3][1] = -1e30f;
        sacc[f][3][2] = -1e30f; sacc[f][3][3] = -1e30f;
      }
    }

    // ---- P = exp2(S), pack 4 consecutive keys -> b64 LDS write ----
#pragma unroll
    for (int f = 0; f < 2; ++f) {
      int ro = (f * 16 + lr) * 72;
#pragma unroll
      for (int ct = 0; ct < 4; ++ct) {
        unsigned u0 = __float_as_uint(exp2f(sacc[f][ct][0]));
        unsigned u1 = __float_as_uint(exp2f(sacc[f][ct][1]));
        unsigned u2 = __float_as_uint(exp2f(sacc[f][ct][2]));
        unsigned u3 = __float_as_uint(exp2f(sacc[f][ct][3]));
        uint2 pk;
        pk.x = __builtin_amdgcn_perm(u1, u0, 0x07060302u);
        pk.y = __builtin_amdgcn_perm(u3, u2, 0x07060302u);
        *(uint2*)&sP[w][ro + ct * 16 + g * 4] = pk;
      }
    }

    // ---- O += P * V^T (c4=4 vs ones-frag accumulates l) ----
    __builtin_amdgcn_s_setprio(1);
#pragma unroll
    for (int kk = 0; kk < 2; ++kk) {
      short8 ap[2];
#pragma unroll
      for (int f = 0; f < 2; ++f)
        ap[f] = *(const short8*)&sP[w][(f * 16 + lr) * 72 + kk * 32 + g * 8];
#pragma unroll
      for (int c4 = 0; c4 < 4; ++c4) {
        int row = c4 * 16 + lr;
        int sw = row & 7;
        short8 bv = *(const short8*)&sV[cur][row * 64 + (((kk * 4 + g) ^ sw) << 3)];
#pragma unroll
        for (int f = 0; f < 2; ++f)
          O[f][c4] = __builtin_amdgcn_mfma_f32_16x16x32_bf16(ap[f], bv, O[f][c4], 0, 0, 0);
      }
#pragma unroll
      for (int f = 0; f < 2; ++f)
        O[f][4] = __builtin_amdgcn_mfma_f32_16x16x32_bf16(ap[f], vones, O[f][4], 0, 0, 0);
    }
    __builtin_amdgcn_s_setprio(0);

    __syncthreads();  // barrier B
    cur ^= 1;
  }

  size_t pbase = (size_t)(bh * 2 + half) * QPAD;
#pragma unroll
  for (int f = 0; f < 2; ++f)
#pragma unroll
    for (int r = 0; r < 4; ++r) {
      int qg = qw + f * 16 + g * 4 + r;
      if (qg >= NTOK) continue;
      float l = O[f][4][r];
      float inv = 1.f / l;
#pragma unroll
      for (int c4 = 0; c4 < 4; ++c4)
        Opart[(pbase + qg) * 64 + c4 * 16 + lr] = f2bf(O[f][c4][r] * inv);
      if (lr == 0) lsum[pbase + qg] = l;
    }
}

// ---------------- combine halves + residual (pure l-weighting) ----------------
__global__ __launch_bounds__(256) void k_comb(const u16* __restrict__ Opart,
                                              const float* __restrict__ lsum,
                                              const u16* __restrict__ Qa,
                                              u16* __restrict__ outA) {
  const int wv = threadIdx.x >> 6, lane = threadIdx.x & 63;
  int rid = blockIdx.x * 4 + wv;
  if (rid >= BHN * NTOK) return;
  int bh = rid / NTOK, qg = rid - bh * NTOK;
  size_t base0 = (size_t)(bh * 2) * QPAD + qg;
  size_t base1 = base0 + QPAD;
  float l0 = lsum[base0], l1 = lsum[base1];
  float inv = 1.f / (l0 + l1);
  float o0 = bf2f(Opart[base0 * 64 + lane]);
  float o1 = bf2f(Opart[base1 * 64 + lane]);
  float v = (l0 * o0 + l1 * o1) * inv;
  if (qg >= 1) v += RESID * bf2f(Qa[((size_t)bh * QPAD + qg) * AUG + lane]);
  int b = bh / HEADS, h = bh - b * HEADS;
  outA[((size_t)(b * NTOK + qg)) * DIM + h * HD + lane] = f2bf(v);
}

// ---------------- launch ----------------
extern "C" void kernel_launch(void* const* d_in, const int* in_sizes, int n_in,
                              void* d_out, int out_size, void* d_ws, size_t ws_size,
                              hipStream_t stream) {
  (void)in_sizes; (void)n_in; (void)out_size; (void)ws_size;
  const float* x      = (const float*)d_in[0];
  const float* qkv_w  = (const float*)d_in[1];
  const float* qkv_b  = (const float*)d_in[2];
  const float* proj_w = (const float*)d_in[3];
  const float* proj_b = (const float*)d_in[4];
  const float* pw_q   = (const float*)d_in[5];
  const float* pw_k   = (const float*)d_in[6];
  const float* pw_v   = (const float*)d_in[7];
  const float* nw_q   = (const float*)d_in[8];
  const float* nb_q   = (const float*)d_in[9];
  const float* nw_k   = (const float*)d_in[10];
  const float* nb_k   = (const float*)d_in[11];
  const float* nw_v   = (const float*)d_in[12];
  const float* nb_v   = (const float*)d_in[13];
  const float* rel_t  = (const float*)d_in[14];
  const float* rel_h  = (const float*)d_in[15];
  const float* rel_w  = (const float*)d_in[16];
  float* out = (float*)d_out;

  char* ws = (char*)d_ws;
  size_t off = 0;
  auto alloc = [&](size_t bytes) -> void* {
    off = (off + 511) & ~(size_t)511;
    void* p = ws + off;
    off += bytes;
    return p;
  };
  u16*   xb     = (u16*)alloc((size_t)MP * DIM * 2);
  u16*   qkvwT  = (u16*)alloc((size_t)DIM3 * DIM * 2);
  u16*   projwT = (u16*)alloc((size_t)DIM * DIM * 2);
  u16*   qkvf   = (u16*)alloc((size_t)3 * BHN * SLAB * 2 + 2048);  // + zero page
  float* pwT    = (float*)alloc((size_t)3 * 27 * 64 * 4);
  u16*   Qa     = (u16*)alloc((size_t)BHN * QPAD * AUG * 2);
  u16*   Ka     = (u16*)alloc((size_t)BHN * NPAD * AUG * 2);
  u16*   Vt     = (u16*)alloc((size_t)BHN * HD * NPAD * 2);
  u16*   attnO  = (u16*)alloc((size_t)MP * DIM * 2);
  u16*   Opart  = (u16*)alloc((size_t)BHN * 2 * QPAD * HD * 2);
  float* lbuf   = (float*)alloc((size_t)BHN * 2 * QPAD * 4);

  // zero page (1024 bf16) read by k_pool's out-of-range conv rows
  hipMemsetAsync(qkvf + (size_t)3 * BHN * SLAB, 0, 2048, stream);

  k_cast_x<<<dim3(MP * DIM / 1024), dim3(256), 0, stream>>>(x, xb);
  k_prep<<<dim3((3 * 27 * 64 + 255) / 256), dim3(256), 0, stream>>>(pw_q, pw_k, pw_v, pwT);
  k_transpose_cast<<<dim3((DIM3 / 32) * (DIM / 32)), dim3(256), 0, stream>>>(qkv_w, qkvwT, DIM, DIM3);
  k_transpose_cast<<<dim3((DIM / 32) * (DIM / 32)), dim3(256), 0, stream>>>(proj_w, projwT, DIM, DIM);

  k_gemm<0><<<dim3(MP / 128, DIM3 / 128), dim3(256), 0, stream>>>(xb, qkvwT, qkv_b, qkvf);

  k_pool<<<dim3(3 * BHN * 29), dim3(256), 0, stream>>>(
      qkvf, pwT, nw_q, nb_q, nw_k, nb_k, nw_v, nb_v,
      Qa, Ka, Vt);

  k_rel<<<dim3(BHN * 25), dim3(256), 0, stream>>>(rel_t, rel_h, rel_w, Qa);

  k_attn<<<dim3(BHN * 26), dim3(256), 0, stream>>>(Qa, Ka, Vt, Opart, lbuf);

  k_comb<<<dim3((BHN * NTOK + 3) / 4), dim3(256), 0, stream>>>(Opart, lbuf, Qa, attnO);

  k_gemm<1><<<dim3(MP / 128, DIM / 128), dim3(256), 0, stream>>>(attnO, projwT, proj_b, out);
}

// Round 9
// 232.590 us; speedup vs baseline: 1.2697x; 1.0514x over previous
//
#include <hip/hip_runtime.h>
#include <cstdint>
#include <cstddef>

typedef __attribute__((ext_vector_type(8))) short short8;
typedef __attribute__((ext_vector_type(4))) short short4v;
typedef __attribute__((ext_vector_type(4))) float f32x4;
typedef unsigned short u16;

#define DI __device__ __forceinline__

// ---------------- problem constants ----------------
constexpr int BATCH = 4;
constexpr int HEADS = 12, HD = 64;
constexpr int NTOK = 1569;          // T*H*W + 1
constexpr int NPAD = 1600;          // kv pad (25*64), qkvf row pad
constexpr int QPAD = 1664;          // q pad (13*128)
constexpr int DIM = 768, DIM3 = 2304;
constexpr int MROWS = BATCH * NTOK; // 6276
constexpr int MP = 6400;            // 50 * 128
constexpr int AUG = 128;            // 64 ch + 8 + 14 + 14 + pad
constexpr int BHN = BATCH * HEADS;  // 48
constexpr float LOG2E = 1.4426950408889634f;
constexpr float QSCALE = 0.125f * LOG2E;  // attn scale folded with log2e (exp2 domain)
constexpr float RESID = 8.0f / LOG2E;     // 1/QSCALE
constexpr float LN_EPS = 1e-5f;
constexpr int SLAB = NPAD * HD;           // 102400 elems per (tau,bh) slab

// ---------------- helpers ----------------
DI u16 f2bf(float x) {
  union { float f; unsigned u; } v; v.f = x;
  unsigned r = v.u + 0x7FFFu + ((v.u >> 16) & 1u);
  return (u16)(r >> 16);
}
DI float bf2f(u16 h) {
  union { unsigned u; float f; } v; v.u = ((unsigned)h) << 16;
  return v.f;
}

typedef const __attribute__((address_space(1))) unsigned int gu32;
typedef __attribute__((address_space(3))) unsigned int lu32;
DI void gld16(const void* g, void* l) {
  __builtin_amdgcn_global_load_lds((gu32*)g, (lu32*)l, 16, 0, 0);
}

// 64-lane sum, all on VALU/DPP (no LDS pipe): row_ror 1/2/4/8 -> row sums,
// ROW_BCAST15 + ROW_BCAST31 -> lane 63 holds total, readlane -> SGPR broadcast.
DI float redsum64_u(float x) {
  int t;
  t = __builtin_amdgcn_update_dpp(__float_as_int(x), __float_as_int(x), 0x121, 0xF, 0xF, false);
  x += __int_as_float(t);
  t = __builtin_amdgcn_update_dpp(__float_as_int(x), __float_as_int(x), 0x122, 0xF, 0xF, false);
  x += __int_as_float(t);
  t = __builtin_amdgcn_update_dpp(__float_as_int(x), __float_as_int(x), 0x124, 0xF, 0xF, false);
  x += __int_as_float(t);
  t = __builtin_amdgcn_update_dpp(__float_as_int(x), __float_as_int(x), 0x128, 0xF, 0xF, false);
  x += __int_as_float(t);
  t = __builtin_amdgcn_update_dpp(__float_as_int(x), __float_as_int(x), 0x142, 0xF, 0xF, false);
  x += __int_as_float(t);  // row_bcast15
  t = __builtin_amdgcn_update_dpp(__float_as_int(x), __float_as_int(x), 0x143, 0xF, 0xF, false);
  x += __int_as_float(t);  // row_bcast31
  return __int_as_float(__builtin_amdgcn_readlane(__float_as_int(x), 63));
}

// ---------------- cast / prep kernels ----------------
__global__ __launch_bounds__(256) void k_cast_x(const float* __restrict__ x,
                                                u16* __restrict__ xb) {
  int i = (blockIdx.x * 256 + threadIdx.x) * 4;
  if (i >= MP * DIM) return;
  int row = i / DIM;
  short4v o;
  if (row < MROWS) {
    float4 v = *(const float4*)(x + i);
    o.x = (short)f2bf(v.x); o.y = (short)f2bf(v.y);
    o.z = (short)f2bf(v.z); o.w = (short)f2bf(v.w);
  } else {
    o.x = 0; o.y = 0; o.z = 0; o.w = 0;
  }
  *(short4v*)(xb + i) = o;
}

// transpose depthwise conv weights (HD,27) -> (tau,27,HD) for coalesced loads
__global__ __launch_bounds__(256) void k_prep(const float* __restrict__ pq,
                                              const float* __restrict__ pk,
                                              const float* __restrict__ pv,
                                              float* __restrict__ pwT) {
  int i = blockIdx.x * 256 + threadIdx.x;
  if (i >= 3 * 27 * 64) return;
  int tau = i / (27 * 64), r = i % (27 * 64);
  int tap = r >> 6, c = r & 63;
  const float* src = tau == 0 ? pq : tau == 1 ? pk : pv;
  pwT[i] = src[c * 27 + tap];
}

// dst (NC, K) bf16 = transpose of src (K, NC) f32 — LDS 32x32 tile transpose
__global__ __launch_bounds__(256) void k_transpose_cast(const float* __restrict__ src,
                                                        u16* __restrict__ dst,
                                                        int K, int NC) {
  __shared__ float tile[32][33];
  const int ntiles = NC >> 5;
  const int bx = blockIdx.x % ntiles;  // n-tile
  const int by = blockIdx.x / ntiles;  // k-tile
  const int tx = threadIdx.x & 31, ty = threadIdx.x >> 5;
  const int n0 = bx * 32, k0 = by * 32;
#pragma unroll
  for (int r = 0; r < 32; r += 8)
    tile[ty + r][tx] = src[(size_t)(k0 + ty + r) * NC + n0 + tx];
  __syncthreads();
#pragma unroll
  for (int r = 0; r < 32; r += 8)
    dst[(size_t)(n0 + ty + r) * K + k0 + tx] = f2bf(tile[tx][ty + r]);
}

// ---------------- GEMM: C(M,N) = A(M,768)*Bt(N,768)^T + bias ----------------
// EPI 0: scatter bf16 to qkv ws (t,b,h,n,c).  EPI 1: linear f32 out (proj).
template <int EPI>
__global__ __launch_bounds__(256) void k_gemm(const u16* __restrict__ A,
                                              const u16* __restrict__ Bt,
                                              const float* __restrict__ bias,
                                              void* __restrict__ outv) {
  __shared__ __align__(16) u16 sA[128 * 64];
  __shared__ __align__(16) u16 sB[128 * 64];
  const int tid = threadIdx.x;
  const int w = tid >> 6, lane = tid & 63;
  const int g = lane >> 4, lr = lane & 15;
  const int brow = blockIdx.x * 128, bcol = blockIdx.y * 128;
  const int wr = w >> 1, wc = w & 1;

  f32x4 acc[4][4];
#pragma unroll
  for (int m = 0; m < 4; ++m)
#pragma unroll
    for (int n = 0; n < 4; ++n) {
      acc[m][n].x = 0.f; acc[m][n].y = 0.f; acc[m][n].z = 0.f; acc[m][n].w = 0.f;
    }

  for (int kt = 0; kt < 12; ++kt) {
    __syncthreads();
#pragma unroll
    for (int j = 0; j < 4; ++j) {
      int cb = (j * 4 + w) * 64;
      int chunk = cb + lane;
      int row = chunk >> 3, ch = chunk & 7;
      int gch = ch ^ (row & 7);
      gld16(A + (size_t)(brow + row) * DIM + kt * 64 + gch * 8, &sA[cb * 8]);
      gld16(Bt + (size_t)(bcol + row) * DIM + kt * 64 + gch * 8, &sB[cb * 8]);
    }
    __syncthreads();

    short8 af[4][2], bfr[4][2];
#pragma unroll
    for (int m = 0; m < 4; ++m) {
      int row = wr * 64 + m * 16 + lr;
      int sw = row & 7;
#pragma unroll
      for (int ks = 0; ks < 2; ++ks)
        af[m][ks] = *(const short8*)&sA[row * 64 + (((ks * 4 + g) ^ sw) * 8)];
    }
#pragma unroll
    for (int n = 0; n < 4; ++n) {
      int row = wc * 64 + n * 16 + lr;
      int sw = row & 7;
#pragma unroll
      for (int ks = 0; ks < 2; ++ks)
        bfr[n][ks] = *(const short8*)&sB[row * 64 + (((ks * 4 + g) ^ sw) * 8)];
    }
#pragma unroll
    for (int m = 0; m < 4; ++m)
#pragma unroll
      for (int n = 0; n < 4; ++n) {
        acc[m][n] = __builtin_amdgcn_mfma_f32_16x16x32_bf16(af[m][0], bfr[n][0], acc[m][n], 0, 0, 0);
        acc[m][n] = __builtin_amdgcn_mfma_f32_16x16x32_bf16(af[m][1], bfr[n][1], acc[m][n], 0, 0, 0);
      }
  }

#pragma unroll
  for (int m = 0; m < 4; ++m)
#pragma unroll
    for (int n = 0; n < 4; ++n) {
      int gj = bcol + wc * 64 + n * 16 + lr;
      float bv = bias[gj];
#pragma unroll
      for (int r = 0; r < 4; ++r) {
        int gm = brow + wr * 64 + m * 16 + g * 4 + r;
        if (gm >= MROWS) continue;
        float v = acc[m][n][r] + bv;
        if (EPI == 0) {
          int t = gj >= 1536 ? 2 : (gj >= 768 ? 1 : 0);
          int rem = gj - t * 768;
          int h = rem >> 6, c = rem & 63;
          int b = gm >= 3 * NTOK ? 3 : (gm >= 2 * NTOK ? 2 : (gm >= NTOK ? 1 : 0));
          int nt = gm - b * NTOK;
          ((u16*)outv)[(((size_t)(t * BATCH + b) * HEADS + h) * NPAD + nt) * HD + c] = f2bf(v);
        } else {
          ((float*)outv)[(size_t)gm * DIM + gj] = v;
        }
      }
    }
}

// ---------------- pool (depthwise conv3d) + LN + aug writes ----------------
// Wave = one (tau, bh, t, h) row; slides 3x3x3 window along w, TWO tokens per
// iteration (independent chains -> 2x ILP). DPP-only LN reduce (no LDS pipe).
__global__ __launch_bounds__(256, 4) void k_pool(
    const u16* __restrict__ qkv,   // bf16 slabs + zero page at end
    const float* __restrict__ pwT, // (tau,27,64) transposed conv weights
    const float* __restrict__ nw_q, const float* __restrict__ nb_q,
    const float* __restrict__ nw_k, const float* __restrict__ nb_k,
    const float* __restrict__ nw_v, const float* __restrict__ nb_v,
    u16* __restrict__ Qa, u16* __restrict__ Ka, u16* __restrict__ Vt) {
  const int wv = threadIdx.x >> 6, lane = threadIdx.x & 63;
  const int unit = blockIdx.x % 29;
  const int taubh = blockIdx.x / 29;
  const int tau = taubh / BHN, bh = taubh % BHN;
  const u16* src = qkv + (size_t)taubh * SLAB;
  const int zoff = (3 * BHN - taubh) * SLAB;   // zero page offset from src (elems)
  const float* nw = tau == 0 ? nw_q : tau == 1 ? nw_k : nw_v;
  const float* nb = tau == 0 ? nb_q : tau == 1 ? nb_k : nb_v;

  if (unit == 28) {
    if (wv == 0) {
      // CLS token (n = 0)
      float val = bf2f(src[lane]);
      float s = redsum64_u(val);
      float sq = redsum64_u(val * val);
      float mean = s * (1.f / 64.f);
      float var = sq * (1.f / 64.f) - mean * mean;
      float ln = (val - mean) * rsqrtf(var + LN_EPS) * nw[lane] + nb[lane];
      if (tau == 0)      { size_t base = (size_t)bh * QPAD * AUG; Qa[base + lane] = f2bf(ln * QSCALE); Qa[base + 64 + lane] = 0; }
      else if (tau == 1) { size_t base = (size_t)bh * NPAD * AUG; Ka[base + lane] = f2bf(ln); Ka[base + 64 + lane] = 0; }
      else               { Vt[((size_t)bh * HD + lane) * NPAD] = f2bf(ln); }
    } else {
      // pad rows -> zero (Qa to QPAD, Ka/Vt to NPAD)
      int lim = (tau == 0) ? QPAD : NPAD;
      for (int n = 1569 + (wv - 1); n < lim; n += 3) {
        if (tau == 0) {
          size_t base = ((size_t)bh * QPAD + n) * AUG;
          Qa[base + lane] = 0; Qa[base + 64 + lane] = 0;
        } else if (tau == 1) {
          size_t base = ((size_t)bh * NPAD + n) * AUG;
          Ka[base + lane] = 0; Ka[base + 64 + lane] = 0;
        } else {
          Vt[((size_t)bh * HD + lane) * NPAD + n] = 0;
        }
      }
    }
    return;
  }

  const int th = unit * 4 + wv;          // 0..111
  const int t = th / 14, hh = th % 14;

  // coalesced weight load from transposed table (27 x 256B contiguous)
  float wt[27];
  {
    const float* wp = pwT + tau * 27 * 64 + lane;
#pragma unroll
    for (int j = 0; j < 27; ++j) wt[j] = wp[j * 64];
  }

  // per-row source offsets (loop-invariant); invalid rows -> zero page
  int roff[9];
#pragma unroll
  for (int dt = 0; dt < 3; ++dt)
#pragma unroll
    for (int dh = 0; dh < 3; ++dh) {
      int tt = t + dt - 1, h2 = hh + dh - 1;
      bool ok = ((unsigned)tt < 8u) && ((unsigned)h2 < 14u);
      roff[dt * 3 + dh] = (ok ? (1 + (tt * 14 + h2) * 14) * HD : zoff) + lane;
    }

  // 4-column window: win[i][0..3] = cols (2k-1, 2k, 2k+1, 2k+2)
  float win[9][4];
#pragma unroll
  for (int i = 0; i < 9; ++i) {
    win[i][0] = 0.f;
    win[i][1] = bf2f(src[roff[i]]);
    win[i][2] = bf2f(src[roff[i] + HD]);
    win[i][3] = bf2f(src[roff[i] + 2 * HD]);
  }

#pragma unroll
  for (int k = 0; k < 7; ++k) {
    const int c0 = 2 * k + 3, c1 = 2 * k + 4;  // prefetch columns
    float nxt0[9], nxt1[9];
#pragma unroll
    for (int i = 0; i < 9; ++i) {
      nxt0[i] = (c0 < 14) ? bf2f(src[roff[i] + c0 * HD]) : 0.f;
      nxt1[i] = (c1 < 14) ? bf2f(src[roff[i] + c1 * HD]) : 0.f;
    }

    // two independent conv trees (tokens 2k and 2k+1)
    float a0 = 0.f, a1 = 0.f, a2 = 0.f;
    float b0 = 0.f, b1 = 0.f, b2 = 0.f;
#pragma unroll
    for (int i = 0; i < 9; i += 3) {
      a0 += win[i][0] * wt[i * 3 + 0] + win[i][1] * wt[i * 3 + 1] + win[i][2] * wt[i * 3 + 2];
      a1 += win[i + 1][0] * wt[i * 3 + 3] + win[i + 1][1] * wt[i * 3 + 4] + win[i + 1][2] * wt[i * 3 + 5];
      a2 += win[i + 2][0] * wt[i * 3 + 6] + win[i + 2][1] * wt[i * 3 + 7] + win[i + 2][2] * wt[i * 3 + 8];
      b0 += win[i][1] * wt[i * 3 + 0] + win[i][2] * wt[i * 3 + 1] + win[i][3] * wt[i * 3 + 2];
      b1 += win[i + 1][1] * wt[i * 3 + 3] + win[i + 1][2] * wt[i * 3 + 4] + win[i + 1][3] * wt[i * 3 + 5];
      b2 += win[i + 2][1] * wt[i * 3 + 6] + win[i + 2][2] * wt[i * 3 + 7] + win[i + 2][3] * wt[i * 3 + 8];
    }
    float va = (a0 + a1) + a2;
    float vb = (b0 + b1) + b2;

    // two independent LN chains (DPP-only reduces)
    float sa = redsum64_u(va), sqa = redsum64_u(va * va);
    float sb = redsum64_u(vb), sqb = redsum64_u(vb * vb);
    float ma = sa * (1.f / 64.f), va_ = sqa * (1.f / 64.f) - ma * ma;
    float mb = sb * (1.f / 64.f), vb_ = sqb * (1.f / 64.f) - mb * mb;
    float lna = (va - ma) * rsqrtf(va_ + LN_EPS) * nw[lane] + nb[lane];
    float lnb = (vb - mb) * rsqrtf(vb_ + LN_EPS) * nw[lane] + nb[lane];

    const int n = 1 + (t * 14 + hh) * 14 + 2 * k;
    if (tau == 0) {
      size_t base = ((size_t)bh * QPAD + n) * AUG;
      Qa[base + lane] = f2bf(lna * QSCALE);
      Qa[base + 64 + lane] = 0;
      Qa[base + AUG + lane] = f2bf(lnb * QSCALE);
      Qa[base + AUG + 64 + lane] = 0;
    } else if (tau == 1) {
      size_t base = ((size_t)bh * NPAD + n) * AUG;
      Ka[base + lane] = f2bf(lna);
      Ka[base + AUG + lane] = f2bf(lnb);
      u16 ea = 0, eb = 0;
      if (lane == t || lane == 8 + hh) { ea = 0x3F80; eb = 0x3F80; }
      if (lane == 22 + 2 * k) ea = 0x3F80;
      if (lane == 23 + 2 * k) eb = 0x3F80;
      Ka[base + 64 + lane] = ea;
      Ka[base + AUG + 64 + lane] = eb;
    } else {
      size_t vb2 = ((size_t)bh * HD + lane) * NPAD + n;
      Vt[vb2] = f2bf(lna);
      Vt[vb2 + 1] = f2bf(lnb);
    }

    // shift window by 2 columns
#pragma unroll
    for (int i = 0; i < 9; ++i) {
      win[i][0] = win[i][2]; win[i][1] = win[i][3];
      win[i][2] = nxt0[i];   win[i][3] = nxt1[i];
    }
  }
}

// ---------------- rel-pos dot table via MFMA ----------------
__global__ __launch_bounds__(256) void k_rel(const float* __restrict__ rel_t,
                                             const float* __restrict__ rel_h,
                                             const float* __restrict__ rel_w,
                                             u16* __restrict__ Qa) {
  __shared__ __align__(16) u16 sR[80 * 72];
  const int tid = threadIdx.x, w = tid >> 6, lane = tid & 63;
  const int g = lane >> 4, lr = lane & 15;
  const int bh = blockIdx.x / 25, qt = blockIdx.x % 25;

  for (int idx = tid; idx < 80 * 64; idx += 256) {
    int j = idx >> 6, c = idx & 63;
    float v = 0.f;
    if (j < 15)      v = rel_t[j * HD + c];
    else if (j < 42) v = rel_h[(j - 15) * HD + c];
    else if (j < 69) v = rel_w[(j - 42) * HD + c];
    sR[j * 72 + c] = f2bf(v * 8.f);
  }
  __syncthreads();

  const int q0 = qt * 64 + w * 16;
  short8 aq[2];
  {
    const u16* qrow = Qa + ((size_t)bh * QPAD + q0 + lr) * AUG;
    aq[0] = *(const short8*)(qrow + g * 8);
    aq[1] = *(const short8*)(qrow + 32 + g * 8);
  }

  f32x4 acc[5];
#pragma unroll
  for (int jt = 0; jt < 5; ++jt) {
    f32x4 a; a.x = 0.f; a.y = 0.f; a.z = 0.f; a.w = 0.f;
    int row = jt * 16 + lr;
    short8 b0 = *(const short8*)&sR[row * 72 + g * 8];
    short8 b1 = *(const short8*)&sR[row * 72 + (4 + g) * 8];
    a = __builtin_amdgcn_mfma_f32_16x16x32_bf16(aq[0], b0, a, 0, 0, 0);
    a = __builtin_amdgcn_mfma_f32_16x16x32_bf16(aq[1], b1, a, 0, 0, 0);
    acc[jt] = a;
  }

#pragma unroll
  for (int jt = 0; jt < 5; ++jt) {
    int j = jt * 16 + lr;
#pragma unroll
    for (int r = 0; r < 4; ++r) {
      int gq = q0 + g * 4 + r;
      if (gq < 1 || gq >= NTOK) continue;
      int p = gq - 1;
      int t = p / 196, pr = p - t * 196;
      int hh = pr / 14, ww = pr - hh * 14;
      int it = t + 7 - j;
      int ih = hh + 28 - j;
      int iw = ww + 55 - j;
      int i = -1;
      if ((unsigned)it < 8u) i = it;
      else if ((unsigned)ih < 14u) i = 8 + ih;
      else if ((unsigned)iw < 14u) i = 22 + iw;
      if (i >= 0)
        Qa[((size_t)bh * QPAD + gq) * AUG + 64 + i] = f2bf(acc[jt][r]);
    }
  }
}

// ---------------- fused flash attention (KV-split x2, swapped QK, no max-tracking) ----------------
__global__ __launch_bounds__(256, 3) void k_attn(const u16* __restrict__ Qa,
                                                 const u16* __restrict__ Ka,
                                                 const u16* __restrict__ Vt,
                                                 u16* __restrict__ Opart,
                                                 float* __restrict__ lsum) {
  __shared__ __align__(16) u16 sK[64 * 128];     // K_aug tile, single-buffered
  __shared__ __align__(16) u16 sV[2][64 * 64];   // V^T tile, double-buffered
  __shared__ __align__(16) u16 sP[4][32 * 72];   // per-wave P [q][key], stride 72
  const int tid = threadIdx.x, w = tid >> 6, lane = tid & 63;
  const int g = lane >> 4, lr = lane & 15;
  const int bid = blockIdx.x;
  const int swz = (bid & 7) * 156 + (bid >> 3);  // XCD-chunked (1248 = 8*156)
  const int bh = swz / 26, rem2 = swz % 26;
  const int half = rem2 / 13, qt = rem2 % 13;
  const int qw = qt * 128 + w * 32;
  const int kb0 = half * 13;
  const int kbN = half ? 12 : 13;

  short8 aq[2][4];
#pragma unroll
  for (int f = 0; f < 2; ++f) {
    const u16* qrow = Qa + ((size_t)bh * QPAD + qw + f * 16 + lr) * AUG;
#pragma unroll
    for (int ks = 0; ks < 4; ++ks) aq[f][ks] = *(const short8*)(qrow + ks * 32 + g * 8);
  }

  short8 vones;
#pragma unroll
  for (int i = 0; i < 8; ++i) vones[i] = (short)0x3F80;

  const u16* kgp[4];
  u16* kld[4];
#pragma unroll
  for (int j = 0; j < 4; ++j) {
    int idx = j * 256 + tid;
    int row = idx >> 4, ch = idx & 15;
    int gch = ch ^ (row & 7);
    kgp[j] = Ka + ((size_t)bh * NPAD + kb0 * 64 + row) * AUG + gch * 8;
    kld[j] = &sK[(j * 256 + w * 64) * 8];
  }
  const u16* vgp[2];
  int vld[2];
#pragma unroll
  for (int j = 0; j < 2; ++j) {
    int idx = j * 256 + tid;
    int row = idx >> 3, ch = idx & 7;
    int gch = ch ^ (row & 7);
    vgp[j] = Vt + ((size_t)bh * HD + row) * NPAD + kb0 * 64 + gch * 8;
    vld[j] = (j * 256 + w * 64) * 8;
  }

#pragma unroll
  for (int j = 0; j < 4; ++j) { gld16(kgp[j], kld[j]); kgp[j] += 64 * AUG; }
#pragma unroll
  for (int j = 0; j < 2; ++j) { gld16(vgp[j], &sV[0][vld[j]]); vgp[j] += 64; }
  __syncthreads();

  f32x4 O[2][5];
#pragma unroll
  for (int f = 0; f < 2; ++f)
#pragma unroll
    for (int c4 = 0; c4 < 5; ++c4) { O[f][c4].x = 0.f; O[f][c4].y = 0.f; O[f][c4].z = 0.f; O[f][c4].w = 0.f; }

  int cur = 0;
  for (int it = 0; it < kbN; ++it) {
    // ---- S^T = K * Q^T (swapped: D row = key = g*4+r, col = q = lr) ----
    f32x4 sacc[2][4];
    __builtin_amdgcn_s_setprio(1);
#pragma unroll
    for (int ct = 0; ct < 4; ++ct) {
      int row = ct * 16 + lr;
      int sw = row & 7;
      short8 bk[4];
#pragma unroll
      for (int ks = 0; ks < 4; ++ks)
        bk[ks] = *(const short8*)&sK[row * 128 + (((ks * 4 + g) ^ sw) << 3)];
#pragma unroll
      for (int f = 0; f < 2; ++f) {
        f32x4 a; a.x = 0.f; a.y = 0.f; a.z = 0.f; a.w = 0.f;
#pragma unroll
        for (int ks = 0; ks < 4; ++ks)
          a = __builtin_amdgcn_mfma_f32_16x16x32_bf16(bk[ks], aq[f][ks], a, 0, 0, 0);
        sacc[f][ct] = a;
      }
    }
    __builtin_amdgcn_s_setprio(0);
    __syncthreads();  // barrier A: all QK reads of sK done

    if (it + 1 < kbN) {
#pragma unroll
      for (int j = 0; j < 4; ++j) { gld16(kgp[j], kld[j]); kgp[j] += 64 * AUG; }
#pragma unroll
      for (int j = 0; j < 2; ++j) { gld16(vgp[j], &sV[cur ^ 1][vld[j]]); vgp[j] += 64; }
    }

    if (kb0 + it == 24) {  // tail: local keys >= 33 invalid (key = ct*16+g*4+r)
#pragma unroll
      for (int f = 0; f < 2; ++f) {
        sacc[f][2][0] = (g == 0) ? sacc[f][2][0] : -1e30f;
        sacc[f][2][1] = -1e30f; sacc[f][2][2] = -1e30f; sacc[f][2][3] = -1e30f;
        sacc[f][3][0] = -1e30f; sacc[f][3][1] = -1e30f;
        sacc[f][3][2] = -1e30f; sacc[f][3][3] = -1e30f;
      }
    }

    // ---- P = exp2(S), pack 4 consecutive keys -> b64 LDS write ----
#pragma unroll
    for (int f = 0; f < 2; ++f) {
      int ro = (f * 16 + lr) * 72;
#pragma unroll
      for (int ct = 0; ct < 4; ++ct) {
        unsigned u0 = __float_as_uint(exp2f(sacc[f][ct][0]));
        unsigned u1 = __float_as_uint(exp2f(sacc[f][ct][1]));
        unsigned u2 = __float_as_uint(exp2f(sacc[f][ct][2]));
        unsigned u3 = __float_as_uint(exp2f(sacc[f][ct][3]));
        uint2 pk;
        pk.x = __builtin_amdgcn_perm(u1, u0, 0x07060302u);
        pk.y = __builtin_amdgcn_perm(u3, u2, 0x07060302u);
        *(uint2*)&sP[w][ro + ct * 16 + g * 4] = pk;
      }
    }

    // ---- O += P * V^T (c4=4 vs ones-frag accumulates l) ----
    __builtin_amdgcn_s_setprio(1);
#pragma unroll
    for (int kk = 0; kk < 2; ++kk) {
      short8 ap[2];
#pragma unroll
      for (int f = 0; f < 2; ++f)
        ap[f] = *(const short8*)&sP[w][(f * 16 + lr) * 72 + kk * 32 + g * 8];
#pragma unroll
      for (int c4 = 0; c4 < 4; ++c4) {
        int row = c4 * 16 + lr;
        int sw = row & 7;
        short8 bv = *(const short8*)&sV[cur][row * 64 + (((kk * 4 + g) ^ sw) << 3)];
#pragma unroll
        for (int f = 0; f < 2; ++f)
          O[f][c4] = __builtin_amdgcn_mfma_f32_16x16x32_bf16(ap[f], bv, O[f][c4], 0, 0, 0);
      }
#pragma unroll
      for (int f = 0; f < 2; ++f)
        O[f][4] = __builtin_amdgcn_mfma_f32_16x16x32_bf16(ap[f], vones, O[f][4], 0, 0, 0);
    }
    __builtin_amdgcn_s_setprio(0);

    __syncthreads();  // barrier B
    cur ^= 1;
  }

  size_t pbase = (size_t)(bh * 2 + half) * QPAD;
#pragma unroll
  for (int f = 0; f < 2; ++f)
#pragma unroll
    for (int r = 0; r < 4; ++r) {
      int qg = qw + f * 16 + g * 4 + r;
      if (qg >= NTOK) continue;
      float l = O[f][4][r];
      float inv = 1.f / l;
#pragma unroll
      for (int c4 = 0; c4 < 4; ++c4)
        Opart[(pbase + qg) * 64 + c4 * 16 + lr] = f2bf(O[f][c4][r] * inv);
      if (lr == 0) lsum[pbase + qg] = l;
    }
}

// ---------------- combine halves + residual (pure l-weighting) ----------------
__global__ __launch_bounds__(256) void k_comb(const u16* __restrict__ Opart,
                                              const float* __restrict__ lsum,
                                              const u16* __restrict__ Qa,
                                              u16* __restrict__ outA) {
  const int wv = threadIdx.x >> 6, lane = threadIdx.x & 63;
  int rid = blockIdx.x * 4 + wv;
  if (rid >= BHN * NTOK) return;
  int bh = rid / NTOK, qg = rid - bh * NTOK;
  size_t base0 = (size_t)(bh * 2) * QPAD + qg;
  size_t base1 = base0 + QPAD;
  float l0 = lsum[base0], l1 = lsum[base1];
  float inv = 1.f / (l0 + l1);
  float o0 = bf2f(Opart[base0 * 64 + lane]);
  float o1 = bf2f(Opart[base1 * 64 + lane]);
  float v = (l0 * o0 + l1 * o1) * inv;
  if (qg >= 1) v += RESID * bf2f(Qa[((size_t)bh * QPAD + qg) * AUG + lane]);
  int b = bh / HEADS, h = bh - b * HEADS;
  outA[((size_t)(b * NTOK + qg)) * DIM + h * HD + lane] = f2bf(v);
}

// ---------------- launch ----------------
extern "C" void kernel_launch(void* const* d_in, const int* in_sizes, int n_in,
                              void* d_out, int out_size, void* d_ws, size_t ws_size,
                              hipStream_t stream) {
  (void)in_sizes; (void)n_in; (void)out_size; (void)ws_size;
  const float* x      = (const float*)d_in[0];
  const float* qkv_w  = (const float*)d_in[1];
  const float* qkv_b  = (const float*)d_in[2];
  const float* proj_w = (const float*)d_in[3];
  const float* proj_b = (const float*)d_in[4];
  const float* pw_q   = (const float*)d_in[5];
  const float* pw_k   = (const float*)d_in[6];
  const float* pw_v   = (const float*)d_in[7];
  const float* nw_q   = (const float*)d_in[8];
  const float* nb_q   = (const float*)d_in[9];
  const float* nw_k   = (const float*)d_in[10];
  const float* nb_k   = (const float*)d_in[11];
  const float* nw_v   = (const float*)d_in[12];
  const float* nb_v   = (const float*)d_in[13];
  const float* rel_t  = (const float*)d_in[14];
  const float* rel_h  = (const float*)d_in[15];
  const float* rel_w  = (const float*)d_in[16];
  float* out = (float*)d_out;

  char* ws = (char*)d_ws;
  size_t off = 0;
  auto alloc = [&](size_t bytes) -> void* {
    off = (off + 511) & ~(size_t)511;
    void* p = ws + off;
    off += bytes;
    return p;
  };
  u16*   xb     = (u16*)alloc((size_t)MP * DIM * 2);
  u16*   qkvwT  = (u16*)alloc((size_t)DIM3 * DIM * 2);
  u16*   projwT = (u16*)alloc((size_t)DIM * DIM * 2);
  u16*   qkvf   = (u16*)alloc((size_t)3 * BHN * SLAB * 2 + 2048);  // + zero page
  float* pwT    = (float*)alloc((size_t)3 * 27 * 64 * 4);
  u16*   Qa     = (u16*)alloc((size_t)BHN * QPAD * AUG * 2);
  u16*   Ka     = (u16*)alloc((size_t)BHN * NPAD * AUG * 2);
  u16*   Vt     = (u16*)alloc((size_t)BHN * HD * NPAD * 2);
  u16*   attnO  = (u16*)alloc((size_t)MP * DIM * 2);
  u16*   Opart  = (u16*)alloc((size_t)BHN * 2 * QPAD * HD * 2);
  float* lbuf   = (float*)alloc((size_t)BHN * 2 * QPAD * 4);

  // zero page (1024 bf16) read by k_pool's out-of-range conv rows
  hipMemsetAsync(qkvf + (size_t)3 * BHN * SLAB, 0, 2048, stream);

  k_cast_x<<<dim3(MP * DIM / 1024), dim3(256), 0, stream>>>(x, xb);
  k_prep<<<dim3((3 * 27 * 64 + 255) / 256), dim3(256), 0, stream>>>(pw_q, pw_k, pw_v, pwT);
  k_transpose_cast<<<dim3((DIM3 / 32) * (DIM / 32)), dim3(256), 0, stream>>>(qkv_w, qkvwT, DIM, DIM3);
  k_transpose_cast<<<dim3((DIM / 32) * (DIM / 32)), dim3(256), 0, stream>>>(proj_w, projwT, DIM, DIM);

  k_gemm<0><<<dim3(MP / 128, DIM3 / 128), dim3(256), 0, stream>>>(xb, qkvwT, qkv_b, qkvf);

  k_pool<<<dim3(3 * BHN * 29), dim3(256), 0, stream>>>(
      qkvf, pwT, nw_q, nb_q, nw_k, nb_k, nw_v, nb_v,
      Qa, Ka, Vt);

  k_rel<<<dim3(BHN * 25), dim3(256), 0, stream>>>(rel_t, rel_h, rel_w, Qa);

  k_attn<<<dim3(BHN * 26), dim3(256), 0, stream>>>(Qa, Ka, Vt, Opart, lbuf);

  k_comb<<<dim3((BHN * NTOK + 3) / 4), dim3(256), 0, stream>>>(Opart, lbuf, Qa, attnO);

  k_gemm<1><<<dim3(MP / 128, DIM / 128), dim3(256), 0, stream>>>(attnO, projwT, proj_b, out);
}

// Round 10
// 226.795 us; speedup vs baseline: 1.3022x; 1.0256x over previous
//
#include <hip/hip_runtime.h>
#include <cstdint>
#include <cstddef>

typedef __attribute__((ext_vector_type(8))) short short8;
typedef __attribute__((ext_vector_type(4))) short short4v;
typedef __attribute__((ext_vector_type(4))) float f32x4;
typedef unsigned short u16;

#define DI __device__ __forceinline__

// ---------------- problem constants ----------------
constexpr int BATCH = 4;
constexpr int HEADS = 12, HD = 64;
constexpr int NTOK = 1569;          // T*H*W + 1
constexpr int NPAD = 1600;          // kv pad (25*64), qkvf row pad
constexpr int QPAD = 1664;          // q pad (13*128)
constexpr int DIM = 768, DIM3 = 2304;
constexpr int MROWS = BATCH * NTOK; // 6276
constexpr int MP = 6400;            // 50 * 128
constexpr int AUG = 128;            // 64 ch + 8 + 14 + 14 + pad
constexpr int BHN = BATCH * HEADS;  // 48
constexpr float LOG2E = 1.4426950408889634f;
constexpr float QSCALE = 0.125f * LOG2E;  // attn scale folded with log2e (exp2 domain)
constexpr float RESID = 8.0f / LOG2E;     // 1/QSCALE
constexpr float LN_EPS = 1e-5f;
constexpr int SLAB = NPAD * HD;           // 102400 elems per (tau,bh) slab

// ---------------- helpers ----------------
DI u16 f2bf(float x) {
  union { float f; unsigned u; } v; v.f = x;
  unsigned r = v.u + 0x7FFFu + ((v.u >> 16) & 1u);
  return (u16)(r >> 16);
}
DI float bf2f(u16 h) {
  union { unsigned u; float f; } v; v.u = ((unsigned)h) << 16;
  return v.f;
}

typedef const __attribute__((address_space(1))) unsigned int gu32;
typedef __attribute__((address_space(3))) unsigned int lu32;
DI void gld16(const void* g, void* l) {
  __builtin_amdgcn_global_load_lds((gu32*)g, (lu32*)l, 16, 0, 0);
}

// 64-lane sum, all on VALU/DPP (no LDS pipe): row_ror 1/2/4/8 -> row sums,
// ROW_BCAST15 + ROW_BCAST31 -> lane 63 holds total, readlane -> SGPR broadcast.
DI float redsum64_u(float x) {
  int t;
  t = __builtin_amdgcn_update_dpp(__float_as_int(x), __float_as_int(x), 0x121, 0xF, 0xF, false);
  x += __int_as_float(t);
  t = __builtin_amdgcn_update_dpp(__float_as_int(x), __float_as_int(x), 0x122, 0xF, 0xF, false);
  x += __int_as_float(t);
  t = __builtin_amdgcn_update_dpp(__float_as_int(x), __float_as_int(x), 0x124, 0xF, 0xF, false);
  x += __int_as_float(t);
  t = __builtin_amdgcn_update_dpp(__float_as_int(x), __float_as_int(x), 0x128, 0xF, 0xF, false);
  x += __int_as_float(t);
  t = __builtin_amdgcn_update_dpp(__float_as_int(x), __float_as_int(x), 0x142, 0xF, 0xF, false);
  x += __int_as_float(t);  // row_bcast15
  t = __builtin_amdgcn_update_dpp(__float_as_int(x), __float_as_int(x), 0x143, 0xF, 0xF, false);
  x += __int_as_float(t);  // row_bcast31
  return __int_as_float(__builtin_amdgcn_readlane(__float_as_int(x), 63));
}

// ---------------- cast / prep kernels ----------------
__global__ __launch_bounds__(256) void k_cast_x(const float* __restrict__ x,
                                                u16* __restrict__ xb) {
  int i = (blockIdx.x * 256 + threadIdx.x) * 4;
  if (i >= MP * DIM) return;
  int row = i / DIM;
  short4v o;
  if (row < MROWS) {
    float4 v = *(const float4*)(x + i);
    o.x = (short)f2bf(v.x); o.y = (short)f2bf(v.y);
    o.z = (short)f2bf(v.z); o.w = (short)f2bf(v.w);
  } else {
    o.x = 0; o.y = 0; o.z = 0; o.w = 0;
  }
  *(short4v*)(xb + i) = o;
}

// transpose depthwise conv weights (HD,27) -> (tau,27,HD) for coalesced loads
__global__ __launch_bounds__(256) void k_prep(const float* __restrict__ pq,
                                              const float* __restrict__ pk,
                                              const float* __restrict__ pv,
                                              float* __restrict__ pwT) {
  int i = blockIdx.x * 256 + threadIdx.x;
  if (i >= 3 * 27 * 64) return;
  int tau = i / (27 * 64), r = i % (27 * 64);
  int tap = r >> 6, c = r & 63;
  const float* src = tau == 0 ? pq : tau == 1 ? pk : pv;
  pwT[i] = src[c * 27 + tap];
}

// dst (NC, K) bf16 = transpose of src (K, NC) f32 — LDS 32x32 tile transpose
__global__ __launch_bounds__(256) void k_transpose_cast(const float* __restrict__ src,
                                                        u16* __restrict__ dst,
                                                        int K, int NC) {
  __shared__ float tile[32][33];
  const int ntiles = NC >> 5;
  const int bx = blockIdx.x % ntiles;  // n-tile
  const int by = blockIdx.x / ntiles;  // k-tile
  const int tx = threadIdx.x & 31, ty = threadIdx.x >> 5;
  const int n0 = bx * 32, k0 = by * 32;
#pragma unroll
  for (int r = 0; r < 32; r += 8)
    tile[ty + r][tx] = src[(size_t)(k0 + ty + r) * NC + n0 + tx];
  __syncthreads();
#pragma unroll
  for (int r = 0; r < 32; r += 8)
    dst[(size_t)(n0 + ty + r) * K + k0 + tx] = f2bf(tile[tx][ty + r]);
}

// ---------------- GEMM: C(M,N) = A(M,768)*Bt(N,768)^T + bias ----------------
// 2-phase pipeline: stage tile kt+1 into LDS buf^1 BEFORE computing buf (one
// barrier per iter; staging latency hides under ds_read+MFMA of current tile).
// EPI 0: scatter bf16 to qkv ws (t,b,h,n,c).  EPI 1: linear f32 out (proj).
template <int EPI>
__global__ __launch_bounds__(256) void k_gemm(const u16* __restrict__ A,
                                              const u16* __restrict__ Bt,
                                              const float* __restrict__ bias,
                                              void* __restrict__ outv) {
  __shared__ __align__(16) u16 sA[2][128 * 64];
  __shared__ __align__(16) u16 sB[2][128 * 64];
  const int tid = threadIdx.x;
  const int w = tid >> 6, lane = tid & 63;
  const int g = lane >> 4, lr = lane & 15;
  const int brow = blockIdx.x * 128, bcol = blockIdx.y * 128;
  const int wr = w >> 1, wc = w & 1;

  // hoisted staging addresses (advance by 64 elems per K-tile)
  const u16* agp[4];
  const u16* bgp[4];
  int lofs[4];
#pragma unroll
  for (int j = 0; j < 4; ++j) {
    int cb = (j * 4 + w) * 64;
    int chunk = cb + lane;
    int row = chunk >> 3, ch = chunk & 7;
    int gch = ch ^ (row & 7);
    agp[j] = A + (size_t)(brow + row) * DIM + gch * 8;
    bgp[j] = Bt + (size_t)(bcol + row) * DIM + gch * 8;
    lofs[j] = cb * 8;
  }
  auto stage = [&](int buf, int kt) {
#pragma unroll
    for (int j = 0; j < 4; ++j) {
      gld16(agp[j] + kt * 64, &sA[buf][lofs[j]]);
      gld16(bgp[j] + kt * 64, &sB[buf][lofs[j]]);
    }
  };

  f32x4 acc[4][4];
#pragma unroll
  for (int m = 0; m < 4; ++m)
#pragma unroll
    for (int n = 0; n < 4; ++n) {
      acc[m][n].x = 0.f; acc[m][n].y = 0.f; acc[m][n].z = 0.f; acc[m][n].w = 0.f;
    }

  stage(0, 0);
  __syncthreads();

  int cur = 0;
  for (int kt = 0; kt < 12; ++kt) {
    // issue next-tile staging first (other buffer) — overlaps with compute
    if (kt < 11) stage(cur ^ 1, kt + 1);

    short8 af[4][2], bfr[4][2];
#pragma unroll
    for (int m = 0; m < 4; ++m) {
      int row = wr * 64 + m * 16 + lr;
      int sw = row & 7;
#pragma unroll
      for (int ks = 0; ks < 2; ++ks)
        af[m][ks] = *(const short8*)&sA[cur][row * 64 + (((ks * 4 + g) ^ sw) * 8)];
    }
#pragma unroll
    for (int n = 0; n < 4; ++n) {
      int row = wc * 64 + n * 16 + lr;
      int sw = row & 7;
#pragma unroll
      for (int ks = 0; ks < 2; ++ks)
        bfr[n][ks] = *(const short8*)&sB[cur][row * 64 + (((ks * 4 + g) ^ sw) * 8)];
    }
    __builtin_amdgcn_s_setprio(1);
#pragma unroll
    for (int m = 0; m < 4; ++m)
#pragma unroll
      for (int n = 0; n < 4; ++n) {
        acc[m][n] = __builtin_amdgcn_mfma_f32_16x16x32_bf16(af[m][0], bfr[n][0], acc[m][n], 0, 0, 0);
        acc[m][n] = __builtin_amdgcn_mfma_f32_16x16x32_bf16(af[m][1], bfr[n][1], acc[m][n], 0, 0, 0);
      }
    __builtin_amdgcn_s_setprio(0);

    __syncthreads();  // staging landed + all reads of cur done
    cur ^= 1;
  }

#pragma unroll
  for (int m = 0; m < 4; ++m)
#pragma unroll
    for (int n = 0; n < 4; ++n) {
      int gj = bcol + wc * 64 + n * 16 + lr;
      float bv = bias[gj];
#pragma unroll
      for (int r = 0; r < 4; ++r) {
        int gm = brow + wr * 64 + m * 16 + g * 4 + r;
        if (gm >= MROWS) continue;
        float v = acc[m][n][r] + bv;
        if (EPI == 0) {
          int t = gj >= 1536 ? 2 : (gj >= 768 ? 1 : 0);
          int rem = gj - t * 768;
          int h = rem >> 6, c = rem & 63;
          int b = gm >= 3 * NTOK ? 3 : (gm >= 2 * NTOK ? 2 : (gm >= NTOK ? 1 : 0));
          int nt = gm - b * NTOK;
          ((u16*)outv)[(((size_t)(t * BATCH + b) * HEADS + h) * NPAD + nt) * HD + c] = f2bf(v);
        } else {
          ((float*)outv)[(size_t)gm * DIM + gj] = v;
        }
      }
    }
}

// ---------------- pool (depthwise conv3d) + LN + aug writes ----------------
// Wave = one (tau, bh, t, h) row; slides 3x3x3 window along w, TWO tokens per
// iteration (independent chains -> 2x ILP). DPP-only LN reduce (no LDS pipe).
__global__ __launch_bounds__(256, 4) void k_pool(
    const u16* __restrict__ qkv,   // bf16 slabs + zero page at end
    const float* __restrict__ pwT, // (tau,27,64) transposed conv weights
    const float* __restrict__ nw_q, const float* __restrict__ nb_q,
    const float* __restrict__ nw_k, const float* __restrict__ nb_k,
    const float* __restrict__ nw_v, const float* __restrict__ nb_v,
    u16* __restrict__ Qa, u16* __restrict__ Ka, u16* __restrict__ Vt) {
  const int wv = threadIdx.x >> 6, lane = threadIdx.x & 63;
  const int unit = blockIdx.x % 29;
  const int taubh = blockIdx.x / 29;
  const int tau = taubh / BHN, bh = taubh % BHN;
  const u16* src = qkv + (size_t)taubh * SLAB;
  const int zoff = (3 * BHN - taubh) * SLAB;   // zero page offset from src (elems)
  const float* nw = tau == 0 ? nw_q : tau == 1 ? nw_k : nw_v;
  const float* nb = tau == 0 ? nb_q : tau == 1 ? nb_k : nb_v;

  if (unit == 28) {
    if (wv == 0) {
      // CLS token (n = 0)
      float val = bf2f(src[lane]);
      float s = redsum64_u(val);
      float sq = redsum64_u(val * val);
      float mean = s * (1.f / 64.f);
      float var = sq * (1.f / 64.f) - mean * mean;
      float ln = (val - mean) * rsqrtf(var + LN_EPS) * nw[lane] + nb[lane];
      if (tau == 0)      { size_t base = (size_t)bh * QPAD * AUG; Qa[base + lane] = f2bf(ln * QSCALE); Qa[base + 64 + lane] = 0; }
      else if (tau == 1) { size_t base = (size_t)bh * NPAD * AUG; Ka[base + lane] = f2bf(ln); Ka[base + 64 + lane] = 0; }
      else               { Vt[((size_t)bh * HD + lane) * NPAD] = f2bf(ln); }
    } else {
      // pad rows -> zero (Qa to QPAD, Ka/Vt to NPAD)
      int lim = (tau == 0) ? QPAD : NPAD;
      for (int n = 1569 + (wv - 1); n < lim; n += 3) {
        if (tau == 0) {
          size_t base = ((size_t)bh * QPAD + n) * AUG;
          Qa[base + lane] = 0; Qa[base + 64 + lane] = 0;
        } else if (tau == 1) {
          size_t base = ((size_t)bh * NPAD + n) * AUG;
          Ka[base + lane] = 0; Ka[base + 64 + lane] = 0;
        } else {
          Vt[((size_t)bh * HD + lane) * NPAD + n] = 0;
        }
      }
    }
    return;
  }

  const int th = unit * 4 + wv;          // 0..111
  const int t = th / 14, hh = th % 14;

  // coalesced weight load from transposed table (27 x 256B contiguous)
  float wt[27];
  {
    const float* wp = pwT + tau * 27 * 64 + lane;
#pragma unroll
    for (int j = 0; j < 27; ++j) wt[j] = wp[j * 64];
  }

  // per-row source offsets (loop-invariant); invalid rows -> zero page
  int roff[9];
#pragma unroll
  for (int dt = 0; dt < 3; ++dt)
#pragma unroll
    for (int dh = 0; dh < 3; ++dh) {
      int tt = t + dt - 1, h2 = hh + dh - 1;
      bool ok = ((unsigned)tt < 8u) && ((unsigned)h2 < 14u);
      roff[dt * 3 + dh] = (ok ? (1 + (tt * 14 + h2) * 14) * HD : zoff) + lane;
    }

  // 4-column window: win[i][0..3] = cols (2k-1, 2k, 2k+1, 2k+2)
  float win[9][4];
#pragma unroll
  for (int i = 0; i < 9; ++i) {
    win[i][0] = 0.f;
    win[i][1] = bf2f(src[roff[i]]);
    win[i][2] = bf2f(src[roff[i] + HD]);
    win[i][3] = bf2f(src[roff[i] + 2 * HD]);
  }

#pragma unroll
  for (int k = 0; k < 7; ++k) {
    const int c0 = 2 * k + 3, c1 = 2 * k + 4;  // prefetch columns
    float nxt0[9], nxt1[9];
#pragma unroll
    for (int i = 0; i < 9; ++i) {
      nxt0[i] = (c0 < 14) ? bf2f(src[roff[i] + c0 * HD]) : 0.f;
      nxt1[i] = (c1 < 14) ? bf2f(src[roff[i] + c1 * HD]) : 0.f;
    }

    // two independent conv trees (tokens 2k and 2k+1)
    float a0 = 0.f, a1 = 0.f, a2 = 0.f;
    float b0 = 0.f, b1 = 0.f, b2 = 0.f;
#pragma unroll
    for (int i = 0; i < 9; i += 3) {
      a0 += win[i][0] * wt[i * 3 + 0] + win[i][1] * wt[i * 3 + 1] + win[i][2] * wt[i * 3 + 2];
      a1 += win[i + 1][0] * wt[i * 3 + 3] + win[i + 1][1] * wt[i * 3 + 4] + win[i + 1][2] * wt[i * 3 + 5];
      a2 += win[i + 2][0] * wt[i * 3 + 6] + win[i + 2][1] * wt[i * 3 + 7] + win[i + 2][2] * wt[i * 3 + 8];
      b0 += win[i][1] * wt[i * 3 + 0] + win[i][2] * wt[i * 3 + 1] + win[i][3] * wt[i * 3 + 2];
      b1 += win[i + 1][1] * wt[i * 3 + 3] + win[i + 1][2] * wt[i * 3 + 4] + win[i + 1][3] * wt[i * 3 + 5];
      b2 += win[i + 2][1] * wt[i * 3 + 6] + win[i + 2][2] * wt[i * 3 + 7] + win[i + 2][3] * wt[i * 3 + 8];
    }
    float va = (a0 + a1) + a2;
    float vb = (b0 + b1) + b2;

    // two independent LN chains (DPP-only reduces)
    float sa = redsum64_u(va), sqa = redsum64_u(va * va);
    float sb = redsum64_u(vb), sqb = redsum64_u(vb * vb);
    float ma = sa * (1.f / 64.f), va_ = sqa * (1.f / 64.f) - ma * ma;
    float mb = sb * (1.f / 64.f), vb_ = sqb * (1.f / 64.f) - mb * mb;
    float lna = (va - ma) * rsqrtf(va_ + LN_EPS) * nw[lane] + nb[lane];
    float lnb = (vb - mb) * rsqrtf(vb_ + LN_EPS) * nw[lane] + nb[lane];

    const int n = 1 + (t * 14 + hh) * 14 + 2 * k;
    if (tau == 0) {
      size_t base = ((size_t)bh * QPAD + n) * AUG;
      Qa[base + lane] = f2bf(lna * QSCALE);
      Qa[base + 64 + lane] = 0;
      Qa[base + AUG + lane] = f2bf(lnb * QSCALE);
      Qa[base + AUG + 64 + lane] = 0;
    } else if (tau == 1) {
      size_t base = ((size_t)bh * NPAD + n) * AUG;
      Ka[base + lane] = f2bf(lna);
      Ka[base + AUG + lane] = f2bf(lnb);
      u16 ea = 0, eb = 0;
      if (lane == t || lane == 8 + hh) { ea = 0x3F80; eb = 0x3F80; }
      if (lane == 22 + 2 * k) ea = 0x3F80;
      if (lane == 23 + 2 * k) eb = 0x3F80;
      Ka[base + 64 + lane] = ea;
      Ka[base + AUG + 64 + lane] = eb;
    } else {
      size_t vb2 = ((size_t)bh * HD + lane) * NPAD + n;
      Vt[vb2] = f2bf(lna);
      Vt[vb2 + 1] = f2bf(lnb);
    }

    // shift window by 2 columns
#pragma unroll
    for (int i = 0; i < 9; ++i) {
      win[i][0] = win[i][2]; win[i][1] = win[i][3];
      win[i][2] = nxt0[i];   win[i][3] = nxt1[i];
    }
  }
}

// ---------------- rel-pos dot table via MFMA ----------------
__global__ __launch_bounds__(256) void k_rel(const float* __restrict__ rel_t,
                                             const float* __restrict__ rel_h,
                                             const float* __restrict__ rel_w,
                                             u16* __restrict__ Qa) {
  __shared__ __align__(16) u16 sR[80 * 72];
  const int tid = threadIdx.x, w = tid >> 6, lane = tid & 63;
  const int g = lane >> 4, lr = lane & 15;
  const int bh = blockIdx.x / 25, qt = blockIdx.x % 25;

  for (int idx = tid; idx < 80 * 64; idx += 256) {
    int j = idx >> 6, c = idx & 63;
    float v = 0.f;
    if (j < 15)      v = rel_t[j * HD + c];
    else if (j < 42) v = rel_h[(j - 15) * HD + c];
    else if (j < 69) v = rel_w[(j - 42) * HD + c];
    sR[j * 72 + c] = f2bf(v * 8.f);
  }
  __syncthreads();

  const int q0 = qt * 64 + w * 16;
  short8 aq[2];
  {
    const u16* qrow = Qa + ((size_t)bh * QPAD + q0 + lr) * AUG;
    aq[0] = *(const short8*)(qrow + g * 8);
    aq[1] = *(const short8*)(qrow + 32 + g * 8);
  }

  f32x4 acc[5];
#pragma unroll
  for (int jt = 0; jt < 5; ++jt) {
    f32x4 a; a.x = 0.f; a.y = 0.f; a.z = 0.f; a.w = 0.f;
    int row = jt * 16 + lr;
    short8 b0 = *(const short8*)&sR[row * 72 + g * 8];
    short8 b1 = *(const short8*)&sR[row * 72 + (4 + g) * 8];
    a = __builtin_amdgcn_mfma_f32_16x16x32_bf16(aq[0], b0, a, 0, 0, 0);
    a = __builtin_amdgcn_mfma_f32_16x16x32_bf16(aq[1], b1, a, 0, 0, 0);
    acc[jt] = a;
  }

#pragma unroll
  for (int jt = 0; jt < 5; ++jt) {
    int j = jt * 16 + lr;
#pragma unroll
    for (int r = 0; r < 4; ++r) {
      int gq = q0 + g * 4 + r;
      if (gq < 1 || gq >= NTOK) continue;
      int p = gq - 1;
      int t = p / 196, pr = p - t * 196;
      int hh = pr / 14, ww = pr - hh * 14;
      int it = t + 7 - j;
      int ih = hh + 28 - j;
      int iw = ww + 55 - j;
      int i = -1;
      if ((unsigned)it < 8u) i = it;
      else if ((unsigned)ih < 14u) i = 8 + ih;
      else if ((unsigned)iw < 14u) i = 22 + iw;
      if (i >= 0)
        Qa[((size_t)bh * QPAD + gq) * AUG + 64 + i] = f2bf(acc[jt][r]);
    }
  }
}

// ---------------- fused flash attention (KV-split x2, swapped QK, no max-tracking) ----------------
__global__ __launch_bounds__(256, 3) void k_attn(const u16* __restrict__ Qa,
                                                 const u16* __restrict__ Ka,
                                                 const u16* __restrict__ Vt,
                                                 u16* __restrict__ Opart,
                                                 float* __restrict__ lsum) {
  __shared__ __align__(16) u16 sK[64 * 128];     // K_aug tile, single-buffered
  __shared__ __align__(16) u16 sV[2][64 * 64];   // V^T tile, double-buffered
  __shared__ __align__(16) u16 sP[4][32 * 72];   // per-wave P [q][key], stride 72
  const int tid = threadIdx.x, w = tid >> 6, lane = tid & 63;
  const int g = lane >> 4, lr = lane & 15;
  const int bid = blockIdx.x;
  const int swz = (bid & 7) * 156 + (bid >> 3);  // XCD-chunked (1248 = 8*156)
  const int bh = swz / 26, rem2 = swz % 26;
  const int half = rem2 / 13, qt = rem2 % 13;
  const int qw = qt * 128 + w * 32;
  const int kb0 = half * 13;
  const int kbN = half ? 12 : 13;

  short8 aq[2][4];
#pragma unroll
  for (int f = 0; f < 2; ++f) {
    const u16* qrow = Qa + ((size_t)bh * QPAD + qw + f * 16 + lr) * AUG;
#pragma unroll
    for (int ks = 0; ks < 4; ++ks) aq[f][ks] = *(const short8*)(qrow + ks * 32 + g * 8);
  }

  short8 vones;
#pragma unroll
  for (int i = 0; i < 8; ++i) vones[i] = (short)0x3F80;

  const u16* kgp[4];
  u16* kld[4];
#pragma unroll
  for (int j = 0; j < 4; ++j) {
    int idx = j * 256 + tid;
    int row = idx >> 4, ch = idx & 15;
    int gch = ch ^ (row & 7);
    kgp[j] = Ka + ((size_t)bh * NPAD + kb0 * 64 + row) * AUG + gch * 8;
    kld[j] = &sK[(j * 256 + w * 64) * 8];
  }
  const u16* vgp[2];
  int vld[2];
#pragma unroll
  for (int j = 0; j < 2; ++j) {
    int idx = j * 256 + tid;
    int row = idx >> 3, ch = idx & 7;
    int gch = ch ^ (row & 7);
    vgp[j] = Vt + ((size_t)bh * HD + row) * NPAD + kb0 * 64 + gch * 8;
    vld[j] = (j * 256 + w * 64) * 8;
  }

#pragma unroll
  for (int j = 0; j < 4; ++j) { gld16(kgp[j], kld[j]); kgp[j] += 64 * AUG; }
#pragma unroll
  for (int j = 0; j < 2; ++j) { gld16(vgp[j], &sV[0][vld[j]]); vgp[j] += 64; }
  __syncthreads();

  f32x4 O[2][5];
#pragma unroll
  for (int f = 0; f < 2; ++f)
#pragma unroll
    for (int c4 = 0; c4 < 5; ++c4) { O[f][c4].x = 0.f; O[f][c4].y = 0.f; O[f][c4].z = 0.f; O[f][c4].w = 0.f; }

  int cur = 0;
  for (int it = 0; it < kbN; ++it) {
    // ---- S^T = K * Q^T (swapped: D row = key = g*4+r, col = q = lr) ----
    f32x4 sacc[2][4];
    __builtin_amdgcn_s_setprio(1);
#pragma unroll
    for (int ct = 0; ct < 4; ++ct) {
      int row = ct * 16 + lr;
      int sw = row & 7;
      short8 bk[4];
#pragma unroll
      for (int ks = 0; ks < 4; ++ks)
        bk[ks] = *(const short8*)&sK[row * 128 + (((ks * 4 + g) ^ sw) << 3)];
#pragma unroll
      for (int f = 0; f < 2; ++f) {
        f32x4 a; a.x = 0.f; a.y = 0.f; a.z = 0.f; a.w = 0.f;
#pragma unroll
        for (int ks = 0; ks < 4; ++ks)
          a = __builtin_amdgcn_mfma_f32_16x16x32_bf16(bk[ks], aq[f][ks], a, 0, 0, 0);
        sacc[f][ct] = a;
      }
    }
    __builtin_amdgcn_s_setprio(0);
    __syncthreads();  // barrier A: all QK reads of sK done

    if (it + 1 < kbN) {
#pragma unroll
      for (int j = 0; j < 4; ++j) { gld16(kgp[j], kld[j]); kgp[j] += 64 * AUG; }
#pragma unroll
      for (int j = 0; j < 2; ++j) { gld16(vgp[j], &sV[cur ^ 1][vld[j]]); vgp[j] += 64; }
    }

    if (kb0 + it == 24) {  // tail: local keys >= 33 invalid (key = ct*16+g*4+r)
#pragma unroll
      for (int f = 0; f < 2; ++f) {
        sacc[f][2][0] = (g == 0) ? sacc[f][2][0] : -1e30f;
        sacc[f][2][1] = -1e30f; sacc[f][2][2] = -1e30f; sacc[f][2][3] = -1e30f;
        sacc[f][3][0] = -1e30f; sacc[f][3][1] = -1e30f;
        sacc[f][3][2] = -1e30f; sacc[f][3][3] = -1e30f;
      }
    }

    // ---- P = exp2(S), pack 4 consecutive keys -> b64 LDS write ----
#pragma unroll
    for (int f = 0; f < 2; ++f) {
      int ro = (f * 16 + lr) * 72;
#pragma unroll
      for (int ct = 0; ct < 4; ++ct) {
        unsigned u0 = __float_as_uint(exp2f(sacc[f][ct][0]));
        unsigned u1 = __float_as_uint(exp2f(sacc[f][ct][1]));
        unsigned u2 = __float_as_uint(exp2f(sacc[f][ct][2]));
        unsigned u3 = __float_as_uint(exp2f(sacc[f][ct][3]));
        uint2 pk;
        pk.x = __builtin_amdgcn_perm(u1, u0, 0x07060302u);
        pk.y = __builtin_amdgcn_perm(u3, u2, 0x07060302u);
        *(uint2*)&sP[w][ro + ct * 16 + g * 4] = pk;
      }
    }

    // ---- O += P * V^T (c4=4 vs ones-frag accumulates l) ----
    __builtin_amdgcn_s_setprio(1);
#pragma unroll
    for (int kk = 0; kk < 2; ++kk) {
      short8 ap[2];
#pragma unroll
      for (int f = 0; f < 2; ++f)
        ap[f] = *(const short8*)&sP[w][(f * 16 + lr) * 72 + kk * 32 + g * 8];
#pragma unroll
      for (int c4 = 0; c4 < 4; ++c4) {
        int row = c4 * 16 + lr;
        int sw = row & 7;
        short8 bv = *(const short8*)&sV[cur][row * 64 + (((kk * 4 + g) ^ sw) << 3)];
#pragma unroll
        for (int f = 0; f < 2; ++f)
          O[f][c4] = __builtin_amdgcn_mfma_f32_16x16x32_bf16(ap[f], bv, O[f][c4], 0, 0, 0);
      }
#pragma unroll
      for (int f = 0; f < 2; ++f)
        O[f][4] = __builtin_amdgcn_mfma_f32_16x16x32_bf16(ap[f], vones, O[f][4], 0, 0, 0);
    }
    __builtin_amdgcn_s_setprio(0);

    __syncthreads();  // barrier B
    cur ^= 1;
  }

  size_t pbase = (size_t)(bh * 2 + half) * QPAD;
#pragma unroll
  for (int f = 0; f < 2; ++f)
#pragma unroll
    for (int r = 0; r < 4; ++r) {
      int qg = qw + f * 16 + g * 4 + r;
      if (qg >= NTOK) continue;
      float l = O[f][4][r];
      float inv = 1.f / l;
#pragma unroll
      for (int c4 = 0; c4 < 4; ++c4)
        Opart[(pbase + qg) * 64 + c4 * 16 + lr] = f2bf(O[f][c4][r] * inv);
      if (lr == 0) lsum[pbase + qg] = l;
    }
}

// ---------------- combine halves + residual (pure l-weighting) ----------------
__global__ __launch_bounds__(256) void k_comb(const u16* __restrict__ Opart,
                                              const float* __restrict__ lsum,
                                              const u16* __restrict__ Qa,
                                              u16* __restrict__ outA) {
  const int wv = threadIdx.x >> 6, lane = threadIdx.x & 63;
  int rid = blockIdx.x * 4 + wv;
  if (rid >= BHN * NTOK) return;
  int bh = rid / NTOK, qg = rid - bh * NTOK;
  size_t base0 = (size_t)(bh * 2) * QPAD + qg;
  size_t base1 = base0 + QPAD;
  float l0 = lsum[base0], l1 = lsum[base1];
  float inv = 1.f / (l0 + l1);
  float o0 = bf2f(Opart[base0 * 64 + lane]);
  float o1 = bf2f(Opart[base1 * 64 + lane]);
  float v = (l0 * o0 + l1 * o1) * inv;
  if (qg >= 1) v += RESID * bf2f(Qa[((size_t)bh * QPAD + qg) * AUG + lane]);
  int b = bh / HEADS, h = bh - b * HEADS;
  outA[((size_t)(b * NTOK + qg)) * DIM + h * HD + lane] = f2bf(v);
}

// ---------------- launch ----------------
extern "C" void kernel_launch(void* const* d_in, const int* in_sizes, int n_in,
                              void* d_out, int out_size, void* d_ws, size_t ws_size,
                              hipStream_t stream) {
  (void)in_sizes; (void)n_in; (void)out_size; (void)ws_size;
  const float* x      = (const float*)d_in[0];
  const float* qkv_w  = (const float*)d_in[1];
  const float* qkv_b  = (const float*)d_in[2];
  const float* proj_w = (const float*)d_in[3];
  const float* proj_b = (const float*)d_in[4];
  const float* pw_q   = (const float*)d_in[5];
  const float* pw_k   = (const float*)d_in[6];
  const float* pw_v   = (const float*)d_in[7];
  const float* nw_q   = (const float*)d_in[8];
  const float* nb_q   = (const float*)d_in[9];
  const float* nw_k   = (const float*)d_in[10];
  const float* nb_k   = (const float*)d_in[11];
  const float* nw_v   = (const float*)d_in[12];
  const float* nb_v   = (const float*)d_in[13];
  const float* rel_t  = (const float*)d_in[14];
  const float* rel_h  = (const float*)d_in[15];
  const float* rel_w  = (const float*)d_in[16];
  float* out = (float*)d_out;

  char* ws = (char*)d_ws;
  size_t off = 0;
  auto alloc = [&](size_t bytes) -> void* {
    off = (off + 511) & ~(size_t)511;
    void* p = ws + off;
    off += bytes;
    return p;
  };
  u16*   xb     = (u16*)alloc((size_t)MP * DIM * 2);
  u16*   qkvwT  = (u16*)alloc((size_t)DIM3 * DIM * 2);
  u16*   projwT = (u16*)alloc((size_t)DIM * DIM * 2);
  u16*   qkvf   = (u16*)alloc((size_t)3 * BHN * SLAB * 2 + 2048);  // + zero page
  float* pwT    = (float*)alloc((size_t)3 * 27 * 64 * 4);
  u16*   Qa     = (u16*)alloc((size_t)BHN * QPAD * AUG * 2);
  u16*   Ka     = (u16*)alloc((size_t)BHN * NPAD * AUG * 2);
  u16*   Vt     = (u16*)alloc((size_t)BHN * HD * NPAD * 2);
  u16*   attnO  = (u16*)alloc((size_t)MP * DIM * 2);
  u16*   Opart  = (u16*)alloc((size_t)BHN * 2 * QPAD * HD * 2);
  float* lbuf   = (float*)alloc((size_t)BHN * 2 * QPAD * 4);

  // zero page (1024 bf16) read by k_pool's out-of-range conv rows
  hipMemsetAsync(qkvf + (size_t)3 * BHN * SLAB, 0, 2048, stream);

  k_cast_x<<<dim3(MP * DIM / 1024), dim3(256), 0, stream>>>(x, xb);
  k_prep<<<dim3((3 * 27 * 64 + 255) / 256), dim3(256), 0, stream>>>(pw_q, pw_k, pw_v, pwT);
  k_transpose_cast<<<dim3((DIM3 / 32) * (DIM / 32)), dim3(256), 0, stream>>>(qkv_w, qkvwT, DIM, DIM3);
  k_transpose_cast<<<dim3((DIM / 32) * (DIM / 32)), dim3(256), 0, stream>>>(proj_w, projwT, DIM, DIM);

  k_gemm<0><<<dim3(MP / 128, DIM3 / 128), dim3(256), 0, stream>>>(xb, qkvwT, qkv_b, qkvf);

  k_pool<<<dim3(3 * BHN * 29), dim3(256), 0, stream>>>(
      qkvf, pwT, nw_q, nb_q, nw_k, nb_k, nw_v, nb_v,
      Qa, Ka, Vt);

  k_rel<<<dim3(BHN * 25), dim3(256), 0, stream>>>(rel_t, rel_h, rel_w, Qa);

  k_attn<<<dim3(BHN * 26), dim3(256), 0, stream>>>(Qa, Ka, Vt, Opart, lbuf);

  k_comb<<<dim3((BHN * NTOK + 3) / 4), dim3(256), 0, stream>>>(Opart, lbuf, Qa, attnO);

  k_gemm<1><<<dim3(MP / 128, DIM / 128), dim3(256), 0, stream>>>(attnO, projwT, proj_b, out);
}